// Round 8
// baseline (133.617 us; speedup 1.0000x reference)
//
#include <hip/hip_runtime.h>

#define NB 8
#define NN 4096
#define DNF 64
#define NEDGE 1048576
#define DM 64
#define FF 64

#define SPB2 16           // segments per bucket (Pass B block)
#define NBKT2 2048        // buckets
#define NXCD 8
#define OVFCAP 65536

using f32x4 = __attribute__((ext_vector_type(4))) float;
using s16x8 = __attribute__((ext_vector_type(8))) short;

__device__ __forceinline__ unsigned short f2b(float f) {
    union { float f; unsigned u; } v; v.f = f;
    unsigned r = (v.u + 0x7fffu + ((v.u >> 16) & 1u)) >> 16;
    return (unsigned short)r;
}
__device__ __forceinline__ float uif(unsigned u) {
    union { unsigned u; float f; } v; v.u = u;
    return v.f;
}

// Pack W [K x Ncols] (f32 row-major) into MFMA B-fragment order (bf16)
__device__ __forceinline__ void pack_one(const float* __restrict__ W,
                                         unsigned short* __restrict__ out,
                                         int K, int Ncols, int idx) {
    int j = idx & 7;
    int lane = (idx >> 3) & 63;
    int frag = idx >> 9;
    int KS = K >> 5;
    int ks = frag % KS;
    int nt = frag / KS;
    int k = ks * 32 + ((lane >> 4) << 3) + j;
    int col = nt * 16 + (lane & 15);
    out[idx] = f2b(W[k * Ncols + col]);
}

__global__ void pack_all(const float* __restrict__ Wm1, const float* __restrict__ Wm2,
                         const float* __restrict__ Wu1, const float* __restrict__ Wu2,
                         unsigned short* __restrict__ Qw, unsigned short* __restrict__ Pw,
                         unsigned short* __restrict__ Wm2p,
                         unsigned short* __restrict__ Wu1p, unsigned short* __restrict__ Wu2p) {
    int idx = blockIdx.x * 256 + threadIdx.x;
    if (idx < 8192)        pack_one(Wm1,              Qw,   64, 128, idx);
    else if (idx < 16384)  pack_one(Wm1 + 64 * 128,   Pw,   64, 128, idx - 8192);
    else if (idx < 24576)  pack_one(Wm2,              Wm2p, 128, 64, idx - 16384);
    else if (idx < 40960)  pack_one(Wu1,              Wu1p, 128, 128, idx - 24576);
    else                   pack_one(Wu2,              Wu2p, 128, 64, idx - 40960);
}

__global__ void pack_weights(const float* __restrict__ W, unsigned short* __restrict__ out,
                             int K, int Ncols) {
    int idx = blockIdx.x * 256 + threadIdx.x;
    if (idx >= K * Ncols) return;
    pack_one(W, out, K, Ncols, idx);
}

// Q = X @ Wm1[0:64,:] + b1 (bias folded), P = X @ Wm1[64:128,:]  (bf16, 32768 x 128)
__launch_bounds__(256, 4)
__global__ void precompute_pq(const float* __restrict__ X,
                              const unsigned short* __restrict__ Qw,
                              const unsigned short* __restrict__ Pw,
                              const float* __restrict__ b1,
                              unsigned short* __restrict__ Qp,
                              unsigned short* __restrict__ Pp) {
    __shared__ unsigned short A[64][72];
    const int tid = threadIdx.x;
    const int g0 = blockIdx.x * 64;
    for (int i = 0; i < 16; ++i) {
        int idx = i * 256 + tid;
        int node = idx >> 6;
        int f = idx & 63;
        A[node][f] = f2b(X[(size_t)(g0 + node) * DNF + f]);
    }
    __syncthreads();
    const int wave = tid >> 6, lane = tid & 63;
    const int lr = lane & 15, lq = lane >> 4;
    const int arow = wave * 16 + lr;
    s16x8 a[2];
#pragma unroll
    for (int ks = 0; ks < 2; ++ks)
        a[ks] = *reinterpret_cast<const s16x8*>(&A[arow][ks * 32 + lq * 8]);
#pragma unroll
    for (int nt = 0; nt < 8; ++nt) {
        f32x4 accQ = {0.f, 0.f, 0.f, 0.f};
        f32x4 accP = {0.f, 0.f, 0.f, 0.f};
#pragma unroll
        for (int ks = 0; ks < 2; ++ks) {
            s16x8 bq = *reinterpret_cast<const s16x8*>(&Qw[(((nt << 1) + ks) * 64 + lane) * 8]);
            s16x8 bp = *reinterpret_cast<const s16x8*>(&Pw[(((nt << 1) + ks) * 64 + lane) * 8]);
            accQ = __builtin_amdgcn_mfma_f32_16x16x32_bf16(a[ks], bq, accQ, 0, 0, 0);
            accP = __builtin_amdgcn_mfma_f32_16x16x32_bf16(a[ks], bp, accP, 0, 0, 0);
        }
        int col = nt * 16 + lr;
        float bias = b1[col];
#pragma unroll
        for (int j = 0; j < 4; ++j) {
            int row = g0 + wave * 16 + lq * 4 + j;
            Qp[(size_t)row * 128 + col] = f2b(accQ[j] + bias);
            Pp[(size_t)row * 128 + col] = f2b(accP[j]);
        }
    }
}

// Pass A: per-edge append directly into per-(segment,XCD) sub-list.
// payslot layout is XCD-major: every 64B line written by exactly one XCD.
// payload = dst[0:12) | w13[12:25)
template<int CAP>
__launch_bounds__(256, 8)
__global__ void scatter_direct(const int* __restrict__ eb, const int* __restrict__ esrc,
                               const int* __restrict__ edst, const float* __restrict__ evals,
                               unsigned* __restrict__ gcur2, unsigned* __restrict__ payslot,
                               unsigned* __restrict__ ovf_cnt, unsigned* __restrict__ ovf_seg,
                               unsigned* __restrict__ ovf_pay) {
    unsigned xcd;
    asm volatile("s_getreg_b32 %0, hwreg(HW_REG_XCC_ID)" : "=s"(xcd));
    xcd &= (NXCD - 1);
    const int t0 = blockIdx.x * 1024 + threadIdx.x;
    int seg[4]; unsigned pk[4];
#pragma unroll
    for (int k = 0; k < 4; ++k) {
        int e = t0 + k * 256;
        seg[k] = eb[e] * NN + esrc[e];
        unsigned wq = (unsigned)fminf(evals[e] * 8192.0f + 0.5f, 8191.0f);
        pk[k] = (unsigned)edst[e] | (wq << 12);
    }
    unsigned pos[4];
#pragma unroll
    for (int k = 0; k < 4; ++k)
        pos[k] = atomicAdd(&gcur2[(xcd << 15) + seg[k]], 1u);
#pragma unroll
    for (int k = 0; k < 4; ++k) {
        if (pos[k] < (unsigned)CAP) {
            payslot[(size_t)((xcd << 15) + seg[k]) * CAP + pos[k]] = pk[k];
        } else {
            unsigned o = atomicAdd(ovf_cnt, 1u);
            if (o < (unsigned)OVFCAP) { ovf_seg[o] = (unsigned)seg[k]; ovf_pay[o] = pk[k]; }
        }
    }
}

// Pass B: one bucket (16 segments = 16 consecutive nodes) per block.
// No sort: 8-lane prefix over per-XCD counts, coalesced copy into contiguous
// LDS rows, per-segment reduce s = sum w*relu(Q+P), MFMA gathered, fused node MLP.
template<int CAP>
__launch_bounds__(256, 6)
__global__ void bucket16_fused(const unsigned short* __restrict__ Qp,
                               const unsigned short* __restrict__ Pp,
                               const unsigned* __restrict__ payslot,
                               const unsigned* __restrict__ gcur2,
                               const unsigned* __restrict__ ovf_cnt,
                               const unsigned* __restrict__ ovf_seg,
                               const unsigned* __restrict__ ovf_pay,
                               const unsigned short* __restrict__ Wm2p,
                               const float* __restrict__ b2m,
                               const float* __restrict__ X,
                               const unsigned short* __restrict__ Wu1p,
                               const float* __restrict__ bu1,
                               const unsigned short* __restrict__ Wu2p,
                               const float* __restrict__ bu2,
                               float* __restrict__ out) {
    __shared__ unsigned pays[16][128];     // 8*CAP <= 128
    __shared__ unsigned short S[16][136];
    __shared__ unsigned short A1[16][136];
    __shared__ unsigned short Hs[16][136];
    __shared__ unsigned pref[16][8];
    __shared__ unsigned cl[16][8];
    __shared__ unsigned cnts[16];
    __shared__ float SW[16], SC[16];
    const int tid = threadIdx.x, wv = tid >> 6, lane = tid & 63;
    const int bkt = blockIdx.x;
    const int node0 = bkt * SPB2;                 // first seg == first node id
    const int rowbase = (bkt >> 8) << 12;         // batch * NN
    const unsigned novf = ovf_cnt[0];

    // stage node feats into A1[:, 0:64]
#pragma unroll
    for (int i = 0; i < 4; ++i) {
        int idx = i * 256 + tid;
        int row = idx >> 6, f = idx & 63;
        A1[row][f] = f2b(X[(size_t)(node0 + row) * DNF + f]);
    }
    // per-(seg,xcd) counts + 8-lane exclusive prefix (waves 0,1 fully active)
    if (tid < 128) {
        int lo = tid >> 3, x = tid & 7;
        unsigned c = min(gcur2[(x << 15) + node0 + lo], (unsigned)CAP);
        cl[lo][x] = c;
        unsigned s = c;
#pragma unroll
        for (int o = 1; o < 8; o <<= 1) {
            unsigned y = __shfl_up(s, o, 8);
            if ((tid & 7) >= o) s += y;
        }
        pref[lo][x] = s - c;
        if (x == 7) cnts[lo] = s;
    }
    __syncthreads();
    // copy sub-lists into contiguous LDS rows (no atomics, no sort)
    {
        int p = tid >> 1, sub = tid & 1;
        int lo = p >> 3, x = p & 7;
        unsigned c = cl[lo][x];
        unsigned bse = pref[lo][x];
        const unsigned* src = payslot + (size_t)((x << 15) + node0 + lo) * CAP;
        for (unsigned i = sub; i < c; i += 2)
            pays[lo][bse + i] = src[i];
    }
    __syncthreads();

    const unsigned* P32 = reinterpret_cast<const unsigned*>(Pp);
    const unsigned* Q32 = reinterpret_cast<const unsigned*>(Qp);
    for (int si = 0; si < 4; ++si) {
        const int lo = wv * 4 + si;
        const int seg = node0 + lo;
        const unsigned s1 = cnts[lo];
        unsigned qv = Q32[(size_t)seg * 64 + lane];
        float q0 = uif(qv << 16);
        float q1 = uif(qv & 0xffff0000u);
        float acc0 = 0.f, acc1 = 0.f, wsum = 0.f;
        unsigned scnt = s1;

        for (unsigned bse = 0; bse < s1; bse += 8) {
            unsigned pv[8]; float wf[8];
#pragma unroll
            for (int k = 0; k < 8; ++k) {
                unsigned idx = bse + (unsigned)k;
                unsigned c = (idx < s1) ? pays[lo][idx] : 0u;   // wave-uniform broadcast
                wf[k] = (float)((c >> 12) & 8191u) * (1.0f / 8192.0f);
                pv[k] = P32[(size_t)(rowbase + (int)(c & 0xfffu)) * 64 + lane];
            }
#pragma unroll
            for (int k = 0; k < 8; ++k) {
                float p0 = uif(pv[k] << 16);
                float p1 = uif(pv[k] & 0xffff0000u);
                acc0 = fmaf(wf[k], fmaxf(q0 + p0, 0.f), acc0);
                acc1 = fmaf(wf[k], fmaxf(q1 + p1, 0.f), acc1);
                wsum += wf[k];
            }
        }
        if (novf > 0) {                            // normally (near-)empty, guaranteed-correct
            unsigned ncl = min(novf, (unsigned)OVFCAP);
            for (unsigned i = 0; i < ncl; ++i) {
                if (ovf_seg[i] == (unsigned)seg) {
                    unsigned c = ovf_pay[i];
                    float w = (float)((c >> 12) & 8191u) * (1.0f / 8192.0f);
                    unsigned pv = P32[(size_t)(rowbase + (int)(c & 0xfffu)) * 64 + lane];
                    acc0 = fmaf(w, fmaxf(q0 + uif(pv << 16), 0.f), acc0);
                    acc1 = fmaf(w, fmaxf(q1 + uif(pv & 0xffff0000u), 0.f), acc1);
                    wsum += w;
                    scnt += 1;
                }
            }
        }
        unsigned sp = (unsigned)f2b(acc0) | ((unsigned)f2b(acc1) << 16);
        *reinterpret_cast<unsigned*>(&S[lo][2 * lane]) = sp;
        if (lane == 0) {
            SW[lo] = wsum;
            SC[lo] = 1.0f / (float)max(scnt, 1u);
        }
    }
    __syncthreads();

    const int lr = lane & 15, lq = lane >> 4;
    // gathered = (S @ Wm2 + sumw*b2)/cnt -> A1[:, 64:128] (bf16)
    {
        s16x8 a[4];
#pragma unroll
        for (int ks = 0; ks < 4; ++ks)
            a[ks] = *reinterpret_cast<const s16x8*>(&S[lr][ks * 32 + lq * 8]);
        f32x4 acc = {0.f, 0.f, 0.f, 0.f};
#pragma unroll
        for (int ks = 0; ks < 4; ++ks) {
            s16x8 bf = *reinterpret_cast<const s16x8*>(&Wm2p[(((wv << 2) + ks) * 64 + lane) * 8]);
            acc = __builtin_amdgcn_mfma_f32_16x16x32_bf16(a[ks], bf, acc, 0, 0, 0);
        }
        float bb = b2m[wv * 16 + lr];
#pragma unroll
        for (int j = 0; j < 4; ++j) {
            int r = lq * 4 + j;
            float g = (acc[j] + SW[r] * bb) * SC[r];
            A1[r][64 + wv * 16 + lr] = f2b(g);
        }
    }
    __syncthreads();

    // node MLP layer 1: relu([X|gathered] @ Wu1 + bu1) -> Hs
    {
        s16x8 a1[4];
#pragma unroll
        for (int ks = 0; ks < 4; ++ks)
            a1[ks] = *reinterpret_cast<const s16x8*>(&A1[lr][ks * 32 + lq * 8]);
#pragma unroll
        for (int t = 0; t < 2; ++t) {
            int nt = wv * 2 + t;
            f32x4 acc = {0.f, 0.f, 0.f, 0.f};
#pragma unroll
            for (int ks = 0; ks < 4; ++ks) {
                s16x8 bf = *reinterpret_cast<const s16x8*>(&Wu1p[(((nt << 2) + ks) * 64 + lane) * 8]);
                acc = __builtin_amdgcn_mfma_f32_16x16x32_bf16(a1[ks], bf, acc, 0, 0, 0);
            }
            float bias = bu1[nt * 16 + lr];
#pragma unroll
            for (int j = 0; j < 4; ++j) {
                float hh = fmaxf(acc[j] + bias, 0.f);
                Hs[lq * 4 + j][nt * 16 + lr] = f2b(hh);
            }
        }
    }
    __syncthreads();

    // layer 2: Hs @ Wu2 + bu2 -> out
    {
        s16x8 a2[4];
#pragma unroll
        for (int ks = 0; ks < 4; ++ks)
            a2[ks] = *reinterpret_cast<const s16x8*>(&Hs[lr][ks * 32 + lq * 8]);
        f32x4 acc = {0.f, 0.f, 0.f, 0.f};
#pragma unroll
        for (int ks = 0; ks < 4; ++ks) {
            s16x8 bf = *reinterpret_cast<const s16x8*>(&Wu2p[(((wv << 2) + ks) * 64 + lane) * 8]);
            acc = __builtin_amdgcn_mfma_f32_16x16x32_bf16(a2[ks], bf, acc, 0, 0, 0);
        }
        float bias = bu2[wv * 16 + lr];
#pragma unroll
        for (int j = 0; j < 4; ++j)
            out[(size_t)(node0 + lq * 4 + j) * FF + wv * 16 + lr] = acc[j] + bias;
    }
}

// ---------------- legacy fallback (small ws) ----------------

template<int SCALE>
__launch_bounds__(256, 4)
__global__ void node_kernel(const float* __restrict__ node_feats,
                            const float* __restrict__ sums, const float* __restrict__ counts,
                            const unsigned short* __restrict__ W1p, const float* __restrict__ b1,
                            const unsigned short* __restrict__ W2p, const float* __restrict__ b2,
                            float* __restrict__ out) {
    __shared__ unsigned short A1[64][136];
    __shared__ unsigned short Hs[64][136];
    const int tid = threadIdx.x;
    const int g0 = blockIdx.x * 64;
    for (int i = 0; i < 16; ++i) {
        int idx = i * 256 + tid;
        int node = idx >> 6;
        int p = idx & 63;
        int g = g0 + node;
        float2 v;
        if (p < 32) {
            v = *reinterpret_cast<const float2*>(node_feats + (size_t)g * DNF + 2 * p);
        } else {
            float2 s = *reinterpret_cast<const float2*>(sums + (size_t)g * DM + 2 * p - 64);
            if (SCALE) {
                float scale = 1.0f / fmaxf(counts[g], 1.0f);
                s.x *= scale; s.y *= scale;
            }
            v = s;
        }
        unsigned packed = (unsigned)f2b(v.x) | ((unsigned)f2b(v.y) << 16);
        *reinterpret_cast<unsigned*>(&A1[node][2 * p]) = packed;
    }
    __syncthreads();
    const int wave = tid >> 6, lane = tid & 63;
    const int lr = lane & 15, lq = lane >> 4;
    const int arow = wave * 16 + lr;
    s16x8 a[4];
#pragma unroll
    for (int ks = 0; ks < 4; ++ks)
        a[ks] = *reinterpret_cast<const s16x8*>(&A1[arow][ks * 32 + lq * 8]);
#pragma unroll
    for (int nt = 0; nt < 8; ++nt) {
        f32x4 acc = {0.f, 0.f, 0.f, 0.f};
#pragma unroll
        for (int ks = 0; ks < 4; ++ks) {
            s16x8 bf = *reinterpret_cast<const s16x8*>(&W1p[(((nt << 2) + ks) * 64 + lane) * 8]);
            acc = __builtin_amdgcn_mfma_f32_16x16x32_bf16(a[ks], bf, acc, 0, 0, 0);
        }
        float bias = b1[nt * 16 + lr];
#pragma unroll
        for (int j = 0; j < 4; ++j) {
            float h = acc[j] + bias;
            h = h > 0.f ? h : 0.f;
            Hs[wave * 16 + lq * 4 + j][nt * 16 + lr] = f2b(h);
        }
    }
    s16x8 a2[4];
#pragma unroll
    for (int ks = 0; ks < 4; ++ks)
        a2[ks] = *reinterpret_cast<const s16x8*>(&Hs[arow][ks * 32 + lq * 8]);
#pragma unroll
    for (int nt = 0; nt < 4; ++nt) {
        f32x4 acc = {0.f, 0.f, 0.f, 0.f};
#pragma unroll
        for (int ks = 0; ks < 4; ++ks) {
            s16x8 bf = *reinterpret_cast<const s16x8*>(&W2p[(((nt << 2) + ks) * 64 + lane) * 8]);
            acc = __builtin_amdgcn_mfma_f32_16x16x32_bf16(a2[ks], bf, acc, 0, 0, 0);
        }
        float bias = b2[nt * 16 + lr];
#pragma unroll
        for (int j = 0; j < 4; ++j) {
            int g = g0 + wave * 16 + lq * 4 + j;
            out[(size_t)g * FF + nt * 16 + lr] = acc[j] + bias;
        }
    }
}

__launch_bounds__(256, 4)
__global__ void edge_kernel(const float* __restrict__ node_feats,
                            const int* __restrict__ eb, const int* __restrict__ esrc,
                            const int* __restrict__ edst, const float* __restrict__ evals,
                            const unsigned short* __restrict__ W1p, const float* __restrict__ b1,
                            const unsigned short* __restrict__ W2p, const float* __restrict__ b2,
                            float* __restrict__ sums, float* __restrict__ counts) {
    __shared__ unsigned short A1[64][136];
    __shared__ unsigned short Hs[64][136];
    const int tid = threadIdx.x;
    const int e0 = blockIdx.x * 64;
    if (tid < 64) {
        int e = e0 + tid;
        atomicAdd(&counts[eb[e] * NN + esrc[e]], 1.0f);
    }
    for (int i = 0; i < 16; ++i) {
        int idx = i * 256 + tid;
        int edge = idx >> 6;
        int p = idx & 63;
        int e = e0 + edge;
        int b = eb[e];
        const float* row;
        if (p < 32) row = node_feats + ((size_t)b * NN + esrc[e]) * DNF;
        else        row = node_feats + ((size_t)b * NN + edst[e]) * DNF - 64;
        float2 v = *reinterpret_cast<const float2*>(row + 2 * p);
        unsigned packed = (unsigned)f2b(v.x) | ((unsigned)f2b(v.y) << 16);
        *reinterpret_cast<unsigned*>(&A1[edge][2 * p]) = packed;
    }
    __syncthreads();
    const int wave = tid >> 6, lane = tid & 63;
    const int lr = lane & 15, lq = lane >> 4;
    const int arow = wave * 16 + lr;
    s16x8 a[4];
#pragma unroll
    for (int ks = 0; ks < 4; ++ks)
        a[ks] = *reinterpret_cast<const s16x8*>(&A1[arow][ks * 32 + lq * 8]);
#pragma unroll
    for (int nt = 0; nt < 8; ++nt) {
        f32x4 acc = {0.f, 0.f, 0.f, 0.f};
#pragma unroll
        for (int ks = 0; ks < 4; ++ks) {
            s16x8 bf = *reinterpret_cast<const s16x8*>(&W1p[(((nt << 2) + ks) * 64 + lane) * 8]);
            acc = __builtin_amdgcn_mfma_f32_16x16x32_bf16(a[ks], bf, acc, 0, 0, 0);
        }
        float bias = b1[nt * 16 + lr];
#pragma unroll
        for (int j = 0; j < 4; ++j) {
            float h = acc[j] + bias;
            h = h > 0.f ? h : 0.f;
            Hs[wave * 16 + lq * 4 + j][nt * 16 + lr] = f2b(h);
        }
    }
    s16x8 a2[4];
#pragma unroll
    for (int ks = 0; ks < 4; ++ks)
        a2[ks] = *reinterpret_cast<const s16x8*>(&Hs[arow][ks * 32 + lq * 8]);
    float ev[4]; int seg4[4];
#pragma unroll
    for (int j = 0; j < 4; ++j) {
        int r = e0 + wave * 16 + lq * 4 + j;
        ev[j] = evals[r];
        seg4[j] = eb[r] * NN + esrc[r];
    }
#pragma unroll
    for (int nt = 0; nt < 4; ++nt) {
        f32x4 acc = {0.f, 0.f, 0.f, 0.f};
#pragma unroll
        for (int ks = 0; ks < 4; ++ks) {
            s16x8 bf = *reinterpret_cast<const s16x8*>(&W2p[(((nt << 2) + ks) * 64 + lane) * 8]);
            acc = __builtin_amdgcn_mfma_f32_16x16x32_bf16(a2[ks], bf, acc, 0, 0, 0);
        }
        float bias = b2[nt * 16 + lr];
#pragma unroll
        for (int j = 0; j < 4; ++j) {
            float m = (acc[j] + bias) * ev[j];
            atomicAdd(&sums[(size_t)seg4[j] * DM + nt * 16 + lr], m);
        }
    }
}

template<int CAP>
static void launch_direct(const float* node_feats, const int* eb, const int* esrc,
                          const int* edst, const float* evals,
                          const float* Wm1, const float* bm1, const float* Wm2, const float* bm2,
                          const float* Wu1, const float* bu1, const float* Wu2, const float* bu2,
                          float* out, char* ws, hipStream_t stream) {
    const size_t PAYB = (size_t)NXCD * 32768 * CAP * 4;
    unsigned short* Qp      = (unsigned short*)(ws);
    unsigned short* Pp      = (unsigned short*)(ws + 8388608);
    unsigned*       payslot = (unsigned*)(ws + 16777216);
    char*           rest    = ws + 16777216 + PAYB;
    unsigned*       gcur2   = (unsigned*)(rest);                 // 1 MB
    unsigned*       ovf_cnt = (unsigned*)(rest + 1048576);       // 128 B
    unsigned*       ovf_seg = (unsigned*)(rest + 1048704);       // 256 KB
    unsigned*       ovf_pay = (unsigned*)(rest + 1310848);       // 256 KB
    unsigned short* Qw      = (unsigned short*)(rest + 1572992);
    unsigned short* Pw      = (unsigned short*)(rest + 1589376);
    unsigned short* Wu1p    = (unsigned short*)(rest + 1605760);
    unsigned short* Wu2p    = (unsigned short*)(rest + 1638528);
    unsigned short* Wm2p    = (unsigned short*)(rest + 1654912);

    hipMemsetAsync(gcur2, 0, 1048576 + 128, stream);   // gcur2 + ovf_cnt contiguous
    pack_all<<<192, 256, 0, stream>>>(Wm1, Wm2, Wu1, Wu2, Qw, Pw, Wm2p, Wu1p, Wu2p);
    precompute_pq<<<512, 256, 0, stream>>>(node_feats, Qw, Pw, bm1, Qp, Pp);
    scatter_direct<CAP><<<NEDGE / 1024, 256, 0, stream>>>(eb, esrc, edst, evals,
                                                          gcur2, payslot, ovf_cnt, ovf_seg, ovf_pay);
    bucket16_fused<CAP><<<NBKT2, 256, 0, stream>>>(Qp, Pp, payslot, gcur2,
                                                   ovf_cnt, ovf_seg, ovf_pay,
                                                   Wm2p, bm2, node_feats,
                                                   Wu1p, bu1, Wu2p, bu2, out);
}

extern "C" void kernel_launch(void* const* d_in, const int* in_sizes, int n_in,
                              void* d_out, int out_size, void* d_ws, size_t ws_size,
                              hipStream_t stream) {
    const float* node_feats = (const float*)d_in[0];
    const int*   eb    = (const int*)d_in[1];
    const int*   esrc  = (const int*)d_in[2];
    const int*   edst  = (const int*)d_in[3];
    const float* evals = (const float*)d_in[4];
    const float* Wm1 = (const float*)d_in[5];
    const float* bm1 = (const float*)d_in[6];
    const float* Wm2 = (const float*)d_in[7];
    const float* bm2 = (const float*)d_in[8];
    const float* Wu1 = (const float*)d_in[9];
    const float* bu1 = (const float*)d_in[10];
    const float* Wu2 = (const float*)d_in[11];
    const float* bu2 = (const float*)d_in[12];
    float* out = (float*)d_out;
    char* ws = (char*)d_ws;

    const size_t FIXED = 16777216 + 1671296;             // Qp+Pp + (gcur2..weights)
    const size_t NEED16 = FIXED + (size_t)NXCD * 32768 * 16 * 4;   // ~35.2 MB
    const size_t NEED11 = FIXED + (size_t)NXCD * 32768 * 11 * 4;   // ~30.0 MB
    if (ws_size >= NEED16) {
        launch_direct<16>(node_feats, eb, esrc, edst, evals, Wm1, bm1, Wm2, bm2,
                          Wu1, bu1, Wu2, bu2, out, ws, stream);
    } else if (ws_size >= NEED11) {
        launch_direct<11>(node_feats, eb, esrc, edst, evals, Wm1, bm1, Wm2, bm2,
                          Wu1, bu1, Wu2, bu2, out, ws, stream);
    } else {
        float* counts          = (float*)ws;
        unsigned short* W1p    = (unsigned short*)(ws + 131072);
        unsigned short* W2p    = (unsigned short*)(ws + 163840);
        unsigned short* Wu1p   = (unsigned short*)(ws + 180224);
        unsigned short* Wu2p   = (unsigned short*)(ws + 212992);
        hipMemsetAsync(d_out, 0, (size_t)out_size * sizeof(float), stream);
        hipMemsetAsync(counts, 0, 32768 * sizeof(float), stream);
        pack_weights<<<64, 256, 0, stream>>>(Wm1, W1p, 128, 128);
        pack_weights<<<32, 256, 0, stream>>>(Wm2, W2p, 128, 64);
        pack_weights<<<64, 256, 0, stream>>>(Wu1, Wu1p, 128, 128);
        pack_weights<<<32, 256, 0, stream>>>(Wu2, Wu2p, 128, 64);
        edge_kernel<<<NEDGE / 64, 256, 0, stream>>>(node_feats, eb, esrc, edst, evals,
                                                    W1p, bm1, W2p, bm2, out, counts);
        node_kernel<1><<<(NB * NN) / 64, 256, 0, stream>>>(node_feats, out, counts,
                                                           Wu1p, bu1, Wu2p, bu2, out);
    }
}

// Round 9
// 120.003 us; speedup vs baseline: 1.1134x; 1.1134x over previous
//
#include <hip/hip_runtime.h>

#define NB 8
#define NN 4096
#define DNF 64
#define NEDGE 1048576
#define DM 64
#define FF 64

#define NBKT2 2048        // buckets (seg>>4)
#define SPB2 16           // segments per bucket
#define NXCD 8
#define SUBCAP 192        // slots per (bucket,xcd): mean 64, +17 sigma
#define OVFCAP 65536

using f32x4 = __attribute__((ext_vector_type(4))) float;
using s16x8 = __attribute__((ext_vector_type(8))) short;

__device__ __forceinline__ unsigned short f2b(float f) {
    union { float f; unsigned u; } v; v.f = f;
    unsigned r = (v.u + 0x7fffu + ((v.u >> 16) & 1u)) >> 16;
    return (unsigned short)r;
}
__device__ __forceinline__ float uif(unsigned u) {
    union { unsigned u; float f; } v; v.u = u;
    return v.f;
}

// Pack W [K x Ncols] (f32 row-major) into MFMA B-fragment order (bf16)
__device__ __forceinline__ void pack_one(const float* __restrict__ W,
                                         unsigned short* __restrict__ out,
                                         int K, int Ncols, int idx) {
    int j = idx & 7;
    int lane = (idx >> 3) & 63;
    int frag = idx >> 9;
    int KS = K >> 5;
    int ks = frag % KS;
    int nt = frag / KS;
    int k = ks * 32 + ((lane >> 4) << 3) + j;
    int col = nt * 16 + (lane & 15);
    out[idx] = f2b(W[k * Ncols + col]);
}

__global__ void pack_all(const float* __restrict__ Wm1, const float* __restrict__ Wm2,
                         const float* __restrict__ Wu1, const float* __restrict__ Wu2,
                         unsigned short* __restrict__ Qw, unsigned short* __restrict__ Pw,
                         unsigned short* __restrict__ Wm2p,
                         unsigned short* __restrict__ Wu1p, unsigned short* __restrict__ Wu2p) {
    int idx = blockIdx.x * 256 + threadIdx.x;
    if (idx < 8192)        pack_one(Wm1,              Qw,   64, 128, idx);
    else if (idx < 16384)  pack_one(Wm1 + 64 * 128,   Pw,   64, 128, idx - 8192);
    else if (idx < 24576)  pack_one(Wm2,              Wm2p, 128, 64, idx - 16384);
    else if (idx < 40960)  pack_one(Wu1,              Wu1p, 128, 128, idx - 24576);
    else                   pack_one(Wu2,              Wu2p, 128, 64, idx - 40960);
}

__global__ void pack_weights(const float* __restrict__ W, unsigned short* __restrict__ out,
                             int K, int Ncols) {
    int idx = blockIdx.x * 256 + threadIdx.x;
    if (idx >= K * Ncols) return;
    pack_one(W, out, K, Ncols, idx);
}

// Q = X @ Wm1[0:64,:] + b1 (bias folded), P = X @ Wm1[64:128,:]  (bf16, 32768 x 128)
__launch_bounds__(256, 4)
__global__ void precompute_pq(const float* __restrict__ X,
                              const unsigned short* __restrict__ Qw,
                              const unsigned short* __restrict__ Pw,
                              const float* __restrict__ b1,
                              unsigned short* __restrict__ Qp,
                              unsigned short* __restrict__ Pp) {
    __shared__ unsigned short A[64][72];
    const int tid = threadIdx.x;
    const int g0 = blockIdx.x * 64;
    for (int i = 0; i < 16; ++i) {
        int idx = i * 256 + tid;
        int node = idx >> 6;
        int f = idx & 63;
        A[node][f] = f2b(X[(size_t)(g0 + node) * DNF + f]);
    }
    __syncthreads();
    const int wave = tid >> 6, lane = tid & 63;
    const int lr = lane & 15, lq = lane >> 4;
    const int arow = wave * 16 + lr;
    s16x8 a[2];
#pragma unroll
    for (int ks = 0; ks < 2; ++ks)
        a[ks] = *reinterpret_cast<const s16x8*>(&A[arow][ks * 32 + lq * 8]);
#pragma unroll
    for (int nt = 0; nt < 8; ++nt) {
        f32x4 accQ = {0.f, 0.f, 0.f, 0.f};
        f32x4 accP = {0.f, 0.f, 0.f, 0.f};
#pragma unroll
        for (int ks = 0; ks < 2; ++ks) {
            s16x8 bq = *reinterpret_cast<const s16x8*>(&Qw[(((nt << 1) + ks) * 64 + lane) * 8]);
            s16x8 bp = *reinterpret_cast<const s16x8*>(&Pw[(((nt << 1) + ks) * 64 + lane) * 8]);
            accQ = __builtin_amdgcn_mfma_f32_16x16x32_bf16(a[ks], bq, accQ, 0, 0, 0);
            accP = __builtin_amdgcn_mfma_f32_16x16x32_bf16(a[ks], bp, accP, 0, 0, 0);
        }
        int col = nt * 16 + lr;
        float bias = b1[col];
#pragma unroll
        for (int j = 0; j < 4; ++j) {
            int row = g0 + wave * 16 + lq * 4 + j;
            Qp[(size_t)row * 128 + col] = f2b(accQ[j] + bias);
            Pp[(size_t)row * 128 + col] = f2b(accP[j]);
        }
    }
}

// Pass A (R7, proven): per-edge append into per-(bucket,XCD) sub-list.
// Frontier = 2048 lines (128KB) per XCD -> L2-resident, lines fill before eviction.
// payload = dst[0:12) | w13[12:25) | seg_lo4[25:29)
__launch_bounds__(256, 8)
__global__ void scatter_xcd(const int* __restrict__ eb, const int* __restrict__ esrc,
                            const int* __restrict__ edst, const float* __restrict__ evals,
                            unsigned* __restrict__ gcurX, unsigned* __restrict__ payslot,
                            unsigned* __restrict__ ovf_cnt, unsigned* __restrict__ ovf_seg,
                            unsigned* __restrict__ ovf_pay) {
    unsigned xcd;
    asm volatile("s_getreg_b32 %0, hwreg(HW_REG_XCC_ID)" : "=s"(xcd));
    xcd &= (NXCD - 1);
    const int t0 = blockIdx.x * 1024 + threadIdx.x;
    int seg[4]; unsigned pk[4];
#pragma unroll
    for (int k = 0; k < 4; ++k) {
        int e = t0 + k * 256;
        seg[k] = eb[e] * NN + esrc[e];
        unsigned wq = (unsigned)fminf(evals[e] * 8192.0f + 0.5f, 8191.0f);
        pk[k] = (unsigned)edst[e] | (wq << 12) | ((unsigned)(seg[k] & 15) << 25);
    }
    unsigned pos[4];
#pragma unroll
    for (int k = 0; k < 4; ++k)
        pos[k] = atomicAdd(&gcurX[xcd * NBKT2 + (seg[k] >> 4)], 1u);
#pragma unroll
    for (int k = 0; k < 4; ++k) {
        if (pos[k] < (unsigned)SUBCAP) {
            payslot[((size_t)(seg[k] >> 4) * NXCD + xcd) * SUBCAP + pos[k]] = pk[k];
        } else {
            unsigned o = atomicAdd(ovf_cnt, 1u);
            if (o < (unsigned)OVFCAP) { ovf_seg[o] = (unsigned)seg[k]; ovf_pay[o] = pk[k]; }
        }
    }
}

// Pass B: XCD-affine bucket swizzle (each XCD -> one batch -> 1MB P/Q/X windows,
// L2-resident). Single global read of payload (hist during load), LDS->LDS sort,
// per-segment reduce, MFMA gathered, fused node MLP.
__launch_bounds__(256, 6)
__global__ void bucket16_fused(const unsigned short* __restrict__ Qp,
                               const unsigned short* __restrict__ Pp,
                               const unsigned* __restrict__ payslot,
                               const unsigned* __restrict__ gcurX,
                               const unsigned* __restrict__ ovf_cnt,
                               const unsigned* __restrict__ ovf_seg,
                               const unsigned* __restrict__ ovf_pay,
                               const unsigned short* __restrict__ Wm2p,
                               const float* __restrict__ b2m,
                               const float* __restrict__ X,
                               const unsigned short* __restrict__ Wu1p,
                               const float* __restrict__ bu1,
                               const unsigned short* __restrict__ Wu2p,
                               const float* __restrict__ bu2,
                               float* __restrict__ out) {
    __shared__ unsigned raw[NXCD * SUBCAP];
    __shared__ unsigned sorted[NXCD * SUBCAP];
    __shared__ unsigned short S[16][136];
    __shared__ unsigned short A1[16][136];
    __shared__ unsigned short Hs[16][136];
    __shared__ unsigned h4[4][16];
    __shared__ unsigned offs[17];
    __shared__ unsigned curb[16];
    __shared__ unsigned cx[NXCD];
    __shared__ float SW[16], SC[16];
    const int tid = threadIdx.x, wv = tid >> 6, lane = tid & 63;
    // XCD-affine swizzle: blocks round-robin XCDs; give XCD x the buckets of batch x.
    const int bkt = (blockIdx.x & 7) * 256 + (blockIdx.x >> 3);
    const int node0 = bkt * SPB2;                 // first seg == first node id
    const int rowbase = (bkt >> 8) << 12;         // batch * NN
    const unsigned novf = ovf_cnt[0];

    // stage node feats into A1[:, 0:64]
#pragma unroll
    for (int i = 0; i < 4; ++i) {
        int idx = i * 256 + tid;
        int row = idx >> 6, f = idx & 63;
        A1[row][f] = f2b(X[(size_t)(node0 + row) * DNF + f]);
    }
    if (tid < 64) ((unsigned*)h4)[tid] = 0;
    if (tid < NXCD) cx[tid] = min(gcurX[tid * NBKT2 + bkt], (unsigned)SUBCAP);
    __syncthreads();
    // single global pass: load payload into LDS + per-wave hist
    for (int x = 0; x < NXCD; ++x) {
        unsigned c = cx[x];
        for (unsigned i = tid; i < c; i += 256) {
            unsigned v = payslot[((size_t)bkt * NXCD + x) * SUBCAP + i];
            raw[x * SUBCAP + i] = v;
            atomicAdd(&h4[wv][(v >> 25) & 15u], 1u);
        }
    }
    __syncthreads();
    if (tid < 16) {                                // 16-bin scan of summed hist
        int xx = (int)(h4[0][tid] + h4[1][tid] + h4[2][tid] + h4[3][tid]);
#pragma unroll
        for (int o = 1; o < 16; o <<= 1) {
            int y = __shfl_up(xx, o);
            if (tid >= o) xx += y;
        }
        offs[tid + 1] = (unsigned)xx;
        if (tid == 0) offs[0] = 0;
    }
    __syncthreads();
    if (tid < 16) curb[tid] = offs[tid];
    __syncthreads();
    for (int x = 0; x < NXCD; ++x) {               // LDS -> LDS reorder
        unsigned c = cx[x];
        for (unsigned i = tid; i < c; i += 256) {
            unsigned v = raw[x * SUBCAP + i];
            unsigned pos = atomicAdd(&curb[(v >> 25) & 15u], 1u);
            sorted[pos] = v;
        }
    }
    __syncthreads();

    const unsigned* P32 = reinterpret_cast<const unsigned*>(Pp);
    const unsigned* Q32 = reinterpret_cast<const unsigned*>(Qp);
    const unsigned* Pb = P32 + (size_t)rowbase * 64 + lane;
    for (int si = 0; si < 4; ++si) {
        const int lo = wv * 4 + si;
        const int seg = node0 + lo;
        const unsigned s0 = offs[lo], s1 = offs[lo + 1];
        unsigned qv = Q32[(size_t)seg * 64 + lane];
        float q0 = uif(qv << 16);
        float q1 = uif(qv & 0xffff0000u);
        float acc0 = 0.f, acc1 = 0.f, wsum = 0.f;
        unsigned scnt = s1 - s0;

        for (unsigned bse = s0; bse < s1; bse += 8) {
            unsigned pv[8]; float wf[8];
#pragma unroll
            for (int k = 0; k < 8; ++k) {
                unsigned idx = bse + (unsigned)k;
                unsigned c = (idx < s1) ? sorted[idx] : 0u;   // wave-uniform broadcast
                wf[k] = (float)((c >> 12) & 8191u) * (1.0f / 8192.0f);
                pv[k] = Pb[(size_t)(c & 0xfffu) * 64];
            }
#pragma unroll
            for (int k = 0; k < 8; ++k) {
                float p0 = uif(pv[k] << 16);
                float p1 = uif(pv[k] & 0xffff0000u);
                acc0 = fmaf(wf[k], fmaxf(q0 + p0, 0.f), acc0);
                acc1 = fmaf(wf[k], fmaxf(q1 + p1, 0.f), acc1);
                wsum += wf[k];
            }
        }
        if (novf > 0) {                            // normally empty, guaranteed-correct
            unsigned ncl = min(novf, (unsigned)OVFCAP);
            for (unsigned i = 0; i < ncl; ++i) {
                if (ovf_seg[i] == (unsigned)seg) {
                    unsigned c = ovf_pay[i];
                    float w = (float)((c >> 12) & 8191u) * (1.0f / 8192.0f);
                    unsigned pv = Pb[(size_t)(c & 0xfffu) * 64];
                    acc0 = fmaf(w, fmaxf(q0 + uif(pv << 16), 0.f), acc0);
                    acc1 = fmaf(w, fmaxf(q1 + uif(pv & 0xffff0000u), 0.f), acc1);
                    wsum += w;
                    scnt += 1;
                }
            }
        }
        unsigned sp = (unsigned)f2b(acc0) | ((unsigned)f2b(acc1) << 16);
        *reinterpret_cast<unsigned*>(&S[lo][2 * lane]) = sp;
        if (lane == 0) {
            SW[lo] = wsum;
            SC[lo] = 1.0f / (float)max(scnt, 1u);
        }
    }
    __syncthreads();

    const int lr = lane & 15, lq = lane >> 4;
    // gathered = (S @ Wm2 + sumw*b2)/cnt -> A1[:, 64:128] (bf16)
    {
        s16x8 a[4];
#pragma unroll
        for (int ks = 0; ks < 4; ++ks)
            a[ks] = *reinterpret_cast<const s16x8*>(&S[lr][ks * 32 + lq * 8]);
        f32x4 acc = {0.f, 0.f, 0.f, 0.f};
#pragma unroll
        for (int ks = 0; ks < 4; ++ks) {
            s16x8 bf = *reinterpret_cast<const s16x8*>(&Wm2p[(((wv << 2) + ks) * 64 + lane) * 8]);
            acc = __builtin_amdgcn_mfma_f32_16x16x32_bf16(a[ks], bf, acc, 0, 0, 0);
        }
        float bb = b2m[wv * 16 + lr];
#pragma unroll
        for (int j = 0; j < 4; ++j) {
            int r = lq * 4 + j;
            float g = (acc[j] + SW[r] * bb) * SC[r];
            A1[r][64 + wv * 16 + lr] = f2b(g);
        }
    }
    __syncthreads();

    // node MLP layer 1: relu([X|gathered] @ Wu1 + bu1) -> Hs
    {
        s16x8 a1[4];
#pragma unroll
        for (int ks = 0; ks < 4; ++ks)
            a1[ks] = *reinterpret_cast<const s16x8*>(&A1[lr][ks * 32 + lq * 8]);
#pragma unroll
        for (int t = 0; t < 2; ++t) {
            int nt = wv * 2 + t;
            f32x4 acc = {0.f, 0.f, 0.f, 0.f};
#pragma unroll
            for (int ks = 0; ks < 4; ++ks) {
                s16x8 bf = *reinterpret_cast<const s16x8*>(&Wu1p[(((nt << 2) + ks) * 64 + lane) * 8]);
                acc = __builtin_amdgcn_mfma_f32_16x16x32_bf16(a1[ks], bf, acc, 0, 0, 0);
            }
            float bias = bu1[nt * 16 + lr];
#pragma unroll
            for (int j = 0; j < 4; ++j) {
                float hh = fmaxf(acc[j] + bias, 0.f);
                Hs[lq * 4 + j][nt * 16 + lr] = f2b(hh);
            }
        }
    }
    __syncthreads();

    // layer 2: Hs @ Wu2 + bu2 -> out
    {
        s16x8 a2[4];
#pragma unroll
        for (int ks = 0; ks < 4; ++ks)
            a2[ks] = *reinterpret_cast<const s16x8*>(&Hs[lr][ks * 32 + lq * 8]);
        f32x4 acc = {0.f, 0.f, 0.f, 0.f};
#pragma unroll
        for (int ks = 0; ks < 4; ++ks) {
            s16x8 bf = *reinterpret_cast<const s16x8*>(&Wu2p[(((wv << 2) + ks) * 64 + lane) * 8]);
            acc = __builtin_amdgcn_mfma_f32_16x16x32_bf16(a2[ks], bf, acc, 0, 0, 0);
        }
        float bias = bu2[wv * 16 + lr];
#pragma unroll
        for (int j = 0; j < 4; ++j)
            out[(size_t)(node0 + lq * 4 + j) * FF + wv * 16 + lr] = acc[j] + bias;
    }
}

// ---------------- legacy fallback (small ws) ----------------

template<int SCALE>
__launch_bounds__(256, 4)
__global__ void node_kernel(const float* __restrict__ node_feats,
                            const float* __restrict__ sums, const float* __restrict__ counts,
                            const unsigned short* __restrict__ W1p, const float* __restrict__ b1,
                            const unsigned short* __restrict__ W2p, const float* __restrict__ b2,
                            float* __restrict__ out) {
    __shared__ unsigned short A1[64][136];
    __shared__ unsigned short Hs[64][136];
    const int tid = threadIdx.x;
    const int g0 = blockIdx.x * 64;
    for (int i = 0; i < 16; ++i) {
        int idx = i * 256 + tid;
        int node = idx >> 6;
        int p = idx & 63;
        int g = g0 + node;
        float2 v;
        if (p < 32) {
            v = *reinterpret_cast<const float2*>(node_feats + (size_t)g * DNF + 2 * p);
        } else {
            float2 s = *reinterpret_cast<const float2*>(sums + (size_t)g * DM + 2 * p - 64);
            if (SCALE) {
                float scale = 1.0f / fmaxf(counts[g], 1.0f);
                s.x *= scale; s.y *= scale;
            }
            v = s;
        }
        unsigned packed = (unsigned)f2b(v.x) | ((unsigned)f2b(v.y) << 16);
        *reinterpret_cast<unsigned*>(&A1[node][2 * p]) = packed;
    }
    __syncthreads();
    const int wave = tid >> 6, lane = tid & 63;
    const int lr = lane & 15, lq = lane >> 4;
    const int arow = wave * 16 + lr;
    s16x8 a[4];
#pragma unroll
    for (int ks = 0; ks < 4; ++ks)
        a[ks] = *reinterpret_cast<const s16x8*>(&A1[arow][ks * 32 + lq * 8]);
#pragma unroll
    for (int nt = 0; nt < 8; ++nt) {
        f32x4 acc = {0.f, 0.f, 0.f, 0.f};
#pragma unroll
        for (int ks = 0; ks < 4; ++ks) {
            s16x8 bf = *reinterpret_cast<const s16x8*>(&W1p[(((nt << 2) + ks) * 64 + lane) * 8]);
            acc = __builtin_amdgcn_mfma_f32_16x16x32_bf16(a[ks], bf, acc, 0, 0, 0);
        }
        float bias = b1[nt * 16 + lr];
#pragma unroll
        for (int j = 0; j < 4; ++j) {
            float h = acc[j] + bias;
            h = h > 0.f ? h : 0.f;
            Hs[wave * 16 + lq * 4 + j][nt * 16 + lr] = f2b(h);
        }
    }
    s16x8 a2[4];
#pragma unroll
    for (int ks = 0; ks < 4; ++ks)
        a2[ks] = *reinterpret_cast<const s16x8*>(&Hs[arow][ks * 32 + lq * 8]);
#pragma unroll
    for (int nt = 0; nt < 4; ++nt) {
        f32x4 acc = {0.f, 0.f, 0.f, 0.f};
#pragma unroll
        for (int ks = 0; ks < 4; ++ks) {
            s16x8 bf = *reinterpret_cast<const s16x8*>(&W2p[(((nt << 2) + ks) * 64 + lane) * 8]);
            acc = __builtin_amdgcn_mfma_f32_16x16x32_bf16(a2[ks], bf, acc, 0, 0, 0);
        }
        float bias = b2[nt * 16 + lr];
#pragma unroll
        for (int j = 0; j < 4; ++j) {
            int g = g0 + wave * 16 + lq * 4 + j;
            out[(size_t)g * FF + nt * 16 + lr] = acc[j] + bias;
        }
    }
}

__launch_bounds__(256, 4)
__global__ void edge_kernel(const float* __restrict__ node_feats,
                            const int* __restrict__ eb, const int* __restrict__ esrc,
                            const int* __restrict__ edst, const float* __restrict__ evals,
                            const unsigned short* __restrict__ W1p, const float* __restrict__ b1,
                            const unsigned short* __restrict__ W2p, const float* __restrict__ b2,
                            float* __restrict__ sums, float* __restrict__ counts) {
    __shared__ unsigned short A1[64][136];
    __shared__ unsigned short Hs[64][136];
    const int tid = threadIdx.x;
    const int e0 = blockIdx.x * 64;
    if (tid < 64) {
        int e = e0 + tid;
        atomicAdd(&counts[eb[e] * NN + esrc[e]], 1.0f);
    }
    for (int i = 0; i < 16; ++i) {
        int idx = i * 256 + tid;
        int edge = idx >> 6;
        int p = idx & 63;
        int e = e0 + edge;
        int b = eb[e];
        const float* row;
        if (p < 32) row = node_feats + ((size_t)b * NN + esrc[e]) * DNF;
        else        row = node_feats + ((size_t)b * NN + edst[e]) * DNF - 64;
        float2 v = *reinterpret_cast<const float2*>(row + 2 * p);
        unsigned packed = (unsigned)f2b(v.x) | ((unsigned)f2b(v.y) << 16);
        *reinterpret_cast<unsigned*>(&A1[edge][2 * p]) = packed;
    }
    __syncthreads();
    const int wave = tid >> 6, lane = tid & 63;
    const int lr = lane & 15, lq = lane >> 4;
    const int arow = wave * 16 + lr;
    s16x8 a[4];
#pragma unroll
    for (int ks = 0; ks < 4; ++ks)
        a[ks] = *reinterpret_cast<const s16x8*>(&A1[arow][ks * 32 + lq * 8]);
#pragma unroll
    for (int nt = 0; nt < 8; ++nt) {
        f32x4 acc = {0.f, 0.f, 0.f, 0.f};
#pragma unroll
        for (int ks = 0; ks < 4; ++ks) {
            s16x8 bf = *reinterpret_cast<const s16x8*>(&W1p[(((nt << 2) + ks) * 64 + lane) * 8]);
            acc = __builtin_amdgcn_mfma_f32_16x16x32_bf16(a[ks], bf, acc, 0, 0, 0);
        }
        float bias = b1[nt * 16 + lr];
#pragma unroll
        for (int j = 0; j < 4; ++j) {
            float h = acc[j] + bias;
            h = h > 0.f ? h : 0.f;
            Hs[wave * 16 + lq * 4 + j][nt * 16 + lr] = f2b(h);
        }
    }
    s16x8 a2[4];
#pragma unroll
    for (int ks = 0; ks < 4; ++ks)
        a2[ks] = *reinterpret_cast<const s16x8*>(&Hs[arow][ks * 32 + lq * 8]);
    float ev[4]; int seg4[4];
#pragma unroll
    for (int j = 0; j < 4; ++j) {
        int r = e0 + wave * 16 + lq * 4 + j;
        ev[j] = evals[r];
        seg4[j] = eb[r] * NN + esrc[r];
    }
#pragma unroll
    for (int nt = 0; nt < 4; ++nt) {
        f32x4 acc = {0.f, 0.f, 0.f, 0.f};
#pragma unroll
        for (int ks = 0; ks < 4; ++ks) {
            s16x8 bf = *reinterpret_cast<const s16x8*>(&W2p[(((nt << 2) + ks) * 64 + lane) * 8]);
            acc = __builtin_amdgcn_mfma_f32_16x16x32_bf16(a2[ks], bf, acc, 0, 0, 0);
        }
        float bias = b2[nt * 16 + lr];
#pragma unroll
        for (int j = 0; j < 4; ++j) {
            float m = (acc[j] + bias) * ev[j];
            atomicAdd(&sums[(size_t)seg4[j] * DM + nt * 16 + lr], m);
        }
    }
}

extern "C" void kernel_launch(void* const* d_in, const int* in_sizes, int n_in,
                              void* d_out, int out_size, void* d_ws, size_t ws_size,
                              hipStream_t stream) {
    const float* node_feats = (const float*)d_in[0];
    const int*   eb    = (const int*)d_in[1];
    const int*   esrc  = (const int*)d_in[2];
    const int*   edst  = (const int*)d_in[3];
    const float* evals = (const float*)d_in[4];
    const float* Wm1 = (const float*)d_in[5];
    const float* bm1 = (const float*)d_in[6];
    const float* Wm2 = (const float*)d_in[7];
    const float* bm2 = (const float*)d_in[8];
    const float* Wu1 = (const float*)d_in[9];
    const float* bu1 = (const float*)d_in[10];
    const float* Wu2 = (const float*)d_in[11];
    const float* bu2 = (const float*)d_in[12];
    float* out = (float*)d_out;
    char* ws = (char*)d_ws;

    const size_t NEED = 30048384;
    if (ws_size >= NEED) {
        unsigned short* Qp      = (unsigned short*)(ws);              // 8 MB
        unsigned short* Pp      = (unsigned short*)(ws + 8388608);    // 8 MB
        unsigned*       payslot = (unsigned*)(ws + 16777216);         // 2048*8*192*4 = 12 MB
        unsigned*       gcurX   = (unsigned*)(ws + 29360128);         // 8*2048*4 = 64 KB
        unsigned*       ovf_cnt = (unsigned*)(ws + 29425664);         // 128 B
        unsigned*       ovf_seg = (unsigned*)(ws + 29425792);         // 256 KB
        unsigned*       ovf_pay = (unsigned*)(ws + 29687936);         // 256 KB
        unsigned short* Qw      = (unsigned short*)(ws + 29950080);   // 16 KB
        unsigned short* Pw      = (unsigned short*)(ws + 29966464);   // 16 KB
        unsigned short* Wu1p    = (unsigned short*)(ws + 29982848);   // 32 KB
        unsigned short* Wu2p    = (unsigned short*)(ws + 30015616);   // 16 KB
        unsigned short* Wm2p    = (unsigned short*)(ws + 30032000);   // 16 KB

        hipMemsetAsync(gcurX, 0, 65536 + 128, stream);   // gcurX + ovf_cnt contiguous
        pack_all<<<192, 256, 0, stream>>>(Wm1, Wm2, Wu1, Wu2, Qw, Pw, Wm2p, Wu1p, Wu2p);
        precompute_pq<<<512, 256, 0, stream>>>(node_feats, Qw, Pw, bm1, Qp, Pp);
        scatter_xcd<<<NEDGE / 1024, 256, 0, stream>>>(eb, esrc, edst, evals,
                                                      gcurX, payslot, ovf_cnt, ovf_seg, ovf_pay);
        bucket16_fused<<<NBKT2, 256, 0, stream>>>(Qp, Pp, payslot, gcurX,
                                                  ovf_cnt, ovf_seg, ovf_pay,
                                                  Wm2p, bm2, node_feats,
                                                  Wu1p, bu1, Wu2p, bu2, out);
    } else {
        float* counts          = (float*)ws;
        unsigned short* W1p    = (unsigned short*)(ws + 131072);
        unsigned short* W2p    = (unsigned short*)(ws + 163840);
        unsigned short* Wu1p   = (unsigned short*)(ws + 180224);
        unsigned short* Wu2p   = (unsigned short*)(ws + 212992);
        hipMemsetAsync(d_out, 0, (size_t)out_size * sizeof(float), stream);
        hipMemsetAsync(counts, 0, 32768 * sizeof(float), stream);
        pack_weights<<<64, 256, 0, stream>>>(Wm1, W1p, 128, 128);
        pack_weights<<<32, 256, 0, stream>>>(Wm2, W2p, 128, 64);
        pack_weights<<<64, 256, 0, stream>>>(Wu1, Wu1p, 128, 128);
        pack_weights<<<32, 256, 0, stream>>>(Wu2, Wu2p, 128, 64);
        edge_kernel<<<NEDGE / 64, 256, 0, stream>>>(node_feats, eb, esrc, edst, evals,
                                                    W1p, bm1, W2p, bm2, out, counts);
        node_kernel<1><<<(NB * NN) / 64, 256, 0, stream>>>(node_feats, out, counts,
                                                           Wu1p, bu1, Wu2p, bu2, out);
    }
}

// Round 10
// 118.893 us; speedup vs baseline: 1.1238x; 1.0093x over previous
//
#include <hip/hip_runtime.h>

#define NB 8
#define NN 4096
#define DNF 64
#define NEDGE 1048576
#define DM 64
#define FF 64

#define NBKT2 2048        // buckets (seg>>4)
#define SPB2 16           // segments per bucket
#define NXCD 8
#define SUBCAP 176        // slots per (bucket,xcd): mean 64, +15 sigma
#define OVFCAP 32768

using f32x4 = __attribute__((ext_vector_type(4))) float;
using s16x8 = __attribute__((ext_vector_type(8))) short;

__device__ __forceinline__ unsigned short f2b(float f) {
    union { float f; unsigned u; } v; v.f = f;
    unsigned r = (v.u + 0x7fffu + ((v.u >> 16) & 1u)) >> 16;
    return (unsigned short)r;
}
__device__ __forceinline__ float uif(unsigned u) {
    union { unsigned u; float f; } v; v.u = u;
    return v.f;
}

// Pack W [K x Ncols] (f32 row-major) into MFMA B-fragment order (bf16)
__device__ __forceinline__ void pack_one(const float* __restrict__ W,
                                         unsigned short* __restrict__ out,
                                         int K, int Ncols, int idx) {
    int j = idx & 7;
    int lane = (idx >> 3) & 63;
    int frag = idx >> 9;
    int KS = K >> 5;
    int ks = frag % KS;
    int nt = frag / KS;
    int k = ks * 32 + ((lane >> 4) << 3) + j;
    int col = nt * 16 + (lane & 15);
    out[idx] = f2b(W[k * Ncols + col]);
}

__global__ void pack_all(const float* __restrict__ Wm1, const float* __restrict__ Wm2,
                         const float* __restrict__ Wu1, const float* __restrict__ Wu2,
                         unsigned short* __restrict__ Qw, unsigned short* __restrict__ Pw,
                         unsigned short* __restrict__ Wm2p,
                         unsigned short* __restrict__ Wu1p, unsigned short* __restrict__ Wu2p) {
    int idx = blockIdx.x * 256 + threadIdx.x;
    if (idx < 8192)        pack_one(Wm1,              Qw,   64, 128, idx);
    else if (idx < 16384)  pack_one(Wm1 + 64 * 128,   Pw,   64, 128, idx - 8192);
    else if (idx < 24576)  pack_one(Wm2,              Wm2p, 128, 64, idx - 16384);
    else if (idx < 40960)  pack_one(Wu1,              Wu1p, 128, 128, idx - 24576);
    else                   pack_one(Wu2,              Wu2p, 128, 64, idx - 40960);
}

__global__ void pack_weights(const float* __restrict__ W, unsigned short* __restrict__ out,
                             int K, int Ncols) {
    int idx = blockIdx.x * 256 + threadIdx.x;
    if (idx >= K * Ncols) return;
    pack_one(W, out, K, Ncols, idx);
}

// Q = X @ Wm1[0:64,:] + b1 (bias folded), P = X @ Wm1[64:128,:]  (bf16, 32768 x 128)
__launch_bounds__(256, 4)
__global__ void precompute_pq(const float* __restrict__ X,
                              const unsigned short* __restrict__ Qw,
                              const unsigned short* __restrict__ Pw,
                              const float* __restrict__ b1,
                              unsigned short* __restrict__ Qp,
                              unsigned short* __restrict__ Pp) {
    __shared__ unsigned short A[64][72];
    const int tid = threadIdx.x;
    const int g0 = blockIdx.x * 64;
    for (int i = 0; i < 16; ++i) {
        int idx = i * 256 + tid;
        int node = idx >> 6;
        int f = idx & 63;
        A[node][f] = f2b(X[(size_t)(g0 + node) * DNF + f]);
    }
    __syncthreads();
    const int wave = tid >> 6, lane = tid & 63;
    const int lr = lane & 15, lq = lane >> 4;
    const int arow = wave * 16 + lr;
    s16x8 a[2];
#pragma unroll
    for (int ks = 0; ks < 2; ++ks)
        a[ks] = *reinterpret_cast<const s16x8*>(&A[arow][ks * 32 + lq * 8]);
#pragma unroll
    for (int nt = 0; nt < 8; ++nt) {
        f32x4 accQ = {0.f, 0.f, 0.f, 0.f};
        f32x4 accP = {0.f, 0.f, 0.f, 0.f};
#pragma unroll
        for (int ks = 0; ks < 2; ++ks) {
            s16x8 bq = *reinterpret_cast<const s16x8*>(&Qw[(((nt << 1) + ks) * 64 + lane) * 8]);
            s16x8 bp = *reinterpret_cast<const s16x8*>(&Pw[(((nt << 1) + ks) * 64 + lane) * 8]);
            accQ = __builtin_amdgcn_mfma_f32_16x16x32_bf16(a[ks], bq, accQ, 0, 0, 0);
            accP = __builtin_amdgcn_mfma_f32_16x16x32_bf16(a[ks], bp, accP, 0, 0, 0);
        }
        int col = nt * 16 + lr;
        float bias = b1[col];
#pragma unroll
        for (int j = 0; j < 4; ++j) {
            int row = g0 + wave * 16 + lq * 4 + j;
            Qp[(size_t)row * 128 + col] = f2b(accQ[j] + bias);
            Pp[(size_t)row * 128 + col] = f2b(accP[j]);
        }
    }
}

// Pass A: per-edge append into per-(bucket,XCD) sub-list. Counters padded to
// one per 64B line (16x less same-line atomic serialization at home channel).
// payload = dst[0:12) | w13[12:25) | seg_lo4[25:29)
__launch_bounds__(256, 8)
__global__ void scatter_xcd(const int* __restrict__ eb, const int* __restrict__ esrc,
                            const int* __restrict__ edst, const float* __restrict__ evals,
                            unsigned* __restrict__ gcurP, unsigned* __restrict__ payslot,
                            unsigned* __restrict__ ovf_cnt, unsigned* __restrict__ ovf_seg,
                            unsigned* __restrict__ ovf_pay) {
    unsigned xcd;
    asm volatile("s_getreg_b32 %0, hwreg(HW_REG_XCC_ID)" : "=s"(xcd));
    xcd &= (NXCD - 1);
    const int t0 = blockIdx.x * 1024 + threadIdx.x;
    int seg[4]; unsigned pk[4];
#pragma unroll
    for (int k = 0; k < 4; ++k) {
        int e = t0 + k * 256;
        seg[k] = eb[e] * NN + esrc[e];
        unsigned wq = (unsigned)fminf(evals[e] * 8192.0f + 0.5f, 8191.0f);
        pk[k] = (unsigned)edst[e] | (wq << 12) | ((unsigned)(seg[k] & 15) << 25);
    }
    unsigned pos[4];
#pragma unroll
    for (int k = 0; k < 4; ++k)
        pos[k] = atomicAdd(&gcurP[(xcd * NBKT2 + (seg[k] >> 4)) * 16], 1u);
#pragma unroll
    for (int k = 0; k < 4; ++k) {
        if (pos[k] < (unsigned)SUBCAP) {
            payslot[((size_t)(seg[k] >> 4) * NXCD + xcd) * SUBCAP + pos[k]] = pk[k];
        } else {
            unsigned o = atomicAdd(ovf_cnt, 1u);
            if (o < (unsigned)OVFCAP) { ovf_seg[o] = (unsigned)seg[k]; ovf_pay[o] = pk[k]; }
        }
    }
}

// Pass B: one bucket (16 segments = 16 consecutive nodes) per block.
// Wave w owns sub-lists {2w,2w+1}: lane-strided load + per-wave hist,
// per-wave disjoint sort cursors, per-segment reduce, MFMA gathered, fused MLP.
__launch_bounds__(256, 6)
__global__ void bucket16_fused(const unsigned short* __restrict__ Qp,
                               const unsigned short* __restrict__ Pp,
                               const unsigned* __restrict__ payslot,
                               const unsigned* __restrict__ gcurP,
                               const unsigned* __restrict__ ovf_cnt,
                               const unsigned* __restrict__ ovf_seg,
                               const unsigned* __restrict__ ovf_pay,
                               const unsigned short* __restrict__ Wm2p,
                               const float* __restrict__ b2m,
                               const float* __restrict__ X,
                               const unsigned short* __restrict__ Wu1p,
                               const float* __restrict__ bu1,
                               const unsigned short* __restrict__ Wu2p,
                               const float* __restrict__ bu2,
                               float* __restrict__ out) {
    __shared__ unsigned raw[NXCD * SUBCAP];
    __shared__ unsigned sorted[NXCD * SUBCAP];
    __shared__ unsigned short S[16][136];
    __shared__ unsigned short A1[16][136];
    __shared__ unsigned short Hs[16][136];
    __shared__ unsigned h4[4][16];
    __shared__ unsigned curb4[4][16];
    __shared__ unsigned offs[17];
    __shared__ unsigned cx[NXCD];
    __shared__ float SW[16], SC[16];
    const int tid = threadIdx.x, wv = tid >> 6, lane = tid & 63;
    // XCD-affine swizzle: blocks round-robin XCDs; give XCD x the buckets of batch x.
    const int bkt = (blockIdx.x & 7) * 256 + (blockIdx.x >> 3);
    const int node0 = bkt * SPB2;                 // first seg == first node id
    const int rowbase = (bkt >> 8) << 12;         // batch * NN
    const unsigned novf = ovf_cnt[0];

    // stage node feats into A1[:, 0:64]
#pragma unroll
    for (int i = 0; i < 4; ++i) {
        int idx = i * 256 + tid;
        int row = idx >> 6, f = idx & 63;
        A1[row][f] = f2b(X[(size_t)(node0 + row) * DNF + f]);
    }
    if (tid < 64) ((unsigned*)h4)[tid] = 0;
    if (tid < NXCD) cx[tid] = min(gcurP[(tid * NBKT2 + bkt) * 16], (unsigned)SUBCAP);
    __syncthreads();
    // load + per-wave hist: wave w owns sub-lists 2w, 2w+1 (all 4 waves active)
#pragma unroll
    for (int xi = 0; xi < 2; ++xi) {
        int x = wv * 2 + xi;
        unsigned c = cx[x];
        for (unsigned i = lane; i < c; i += 64) {
            unsigned v = payslot[((size_t)bkt * NXCD + x) * SUBCAP + i];
            raw[x * SUBCAP + i] = v;
            atomicAdd(&h4[wv][(v >> 25) & 15u], 1u);
        }
    }
    __syncthreads();
    if (tid < 16) {                                // 16-bin scan of summed hist
        int xx = (int)(h4[0][tid] + h4[1][tid] + h4[2][tid] + h4[3][tid]);
#pragma unroll
        for (int o = 1; o < 16; o <<= 1) {
            int y = __shfl_up(xx, o);
            if (tid >= o) xx += y;
        }
        offs[tid + 1] = (unsigned)xx;
        if (tid == 0) offs[0] = 0;
    }
    __syncthreads();
    if (tid < 64) {                                // per-(wave,bin) disjoint cursors
        int w = tid >> 4, b = tid & 15;
        unsigned base = offs[b];
        for (int w2 = 0; w2 < w; ++w2) base += h4[w2][b];
        curb4[w][b] = base;
    }
    __syncthreads();
#pragma unroll
    for (int xi = 0; xi < 2; ++xi) {               // LDS->LDS reorder, per-wave cursors
        int x = wv * 2 + xi;
        unsigned c = cx[x];
        for (unsigned i = lane; i < c; i += 64) {
            unsigned v = raw[x * SUBCAP + i];
            unsigned pos = atomicAdd(&curb4[wv][(v >> 25) & 15u], 1u);
            sorted[pos] = v;
        }
    }
    __syncthreads();

    const unsigned* P32 = reinterpret_cast<const unsigned*>(Pp);
    const unsigned* Q32 = reinterpret_cast<const unsigned*>(Qp);
    const unsigned* Pb = P32 + (size_t)rowbase * 64 + lane;
    for (int si = 0; si < 4; ++si) {
        const int lo = wv * 4 + si;
        const int seg = node0 + lo;
        const unsigned s0 = offs[lo], s1 = offs[lo + 1];
        unsigned qv = Q32[(size_t)seg * 64 + lane];
        float q0 = uif(qv << 16);
        float q1 = uif(qv & 0xffff0000u);
        float acc0 = 0.f, acc1 = 0.f;
        unsigned scnt = s1 - s0;

        // lane-parallel weight sum (hoisted out of the per-item loop)
        float wl = 0.f;
        for (unsigned i = s0 + lane; i < s1; i += 64)
            wl += (float)((sorted[i] >> 12) & 8191u);
        for (int m2 = 1; m2 < 64; m2 <<= 1) wl += __shfl_xor(wl, m2);
        float wsum = wl * (1.0f / 8192.0f);

        for (unsigned bse = s0; bse < s1; bse += 8) {
            unsigned pv[8]; float wf[8];
#pragma unroll
            for (int k = 0; k < 8; ++k) {
                unsigned idx = bse + (unsigned)k;
                unsigned c = (idx < s1) ? sorted[idx] : 0u;   // wave-uniform broadcast
                wf[k] = (float)((c >> 12) & 8191u) * (1.0f / 8192.0f);
                pv[k] = Pb[(size_t)(c & 0xfffu) * 64];
            }
#pragma unroll
            for (int k = 0; k < 8; ++k) {
                float p0 = uif(pv[k] << 16);
                float p1 = uif(pv[k] & 0xffff0000u);
                acc0 = fmaf(wf[k], fmaxf(q0 + p0, 0.f), acc0);
                acc1 = fmaf(wf[k], fmaxf(q1 + p1, 0.f), acc1);
            }
        }
        if (novf > 0) {                            // normally empty, guaranteed-correct
            unsigned ncl = min(novf, (unsigned)OVFCAP);
            for (unsigned i = 0; i < ncl; ++i) {
                if (ovf_seg[i] == (unsigned)seg) {
                    unsigned c = ovf_pay[i];
                    float w = (float)((c >> 12) & 8191u) * (1.0f / 8192.0f);
                    unsigned pv = Pb[(size_t)(c & 0xfffu) * 64];
                    acc0 = fmaf(w, fmaxf(q0 + uif(pv << 16), 0.f), acc0);
                    acc1 = fmaf(w, fmaxf(q1 + uif(pv & 0xffff0000u), 0.f), acc1);
                    wsum += w;
                    scnt += 1;
                }
            }
        }
        unsigned sp = (unsigned)f2b(acc0) | ((unsigned)f2b(acc1) << 16);
        *reinterpret_cast<unsigned*>(&S[lo][2 * lane]) = sp;
        if (lane == 0) {
            SW[lo] = wsum;
            SC[lo] = 1.0f / (float)max(scnt, 1u);
        }
    }
    __syncthreads();

    const int lr = lane & 15, lq = lane >> 4;
    // gathered = (S @ Wm2 + sumw*b2)/cnt -> A1[:, 64:128] (bf16)
    {
        s16x8 a[4];
#pragma unroll
        for (int ks = 0; ks < 4; ++ks)
            a[ks] = *reinterpret_cast<const s16x8*>(&S[lr][ks * 32 + lq * 8]);
        f32x4 acc = {0.f, 0.f, 0.f, 0.f};
#pragma unroll
        for (int ks = 0; ks < 4; ++ks) {
            s16x8 bf = *reinterpret_cast<const s16x8*>(&Wm2p[(((wv << 2) + ks) * 64 + lane) * 8]);
            acc = __builtin_amdgcn_mfma_f32_16x16x32_bf16(a[ks], bf, acc, 0, 0, 0);
        }
        float bb = b2m[wv * 16 + lr];
#pragma unroll
        for (int j = 0; j < 4; ++j) {
            int r = lq * 4 + j;
            float g = (acc[j] + SW[r] * bb) * SC[r];
            A1[r][64 + wv * 16 + lr] = f2b(g);
        }
    }
    __syncthreads();

    // node MLP layer 1: relu([X|gathered] @ Wu1 + bu1) -> Hs
    {
        s16x8 a1[4];
#pragma unroll
        for (int ks = 0; ks < 4; ++ks)
            a1[ks] = *reinterpret_cast<const s16x8*>(&A1[lr][ks * 32 + lq * 8]);
#pragma unroll
        for (int t = 0; t < 2; ++t) {
            int nt = wv * 2 + t;
            f32x4 acc = {0.f, 0.f, 0.f, 0.f};
#pragma unroll
            for (int ks = 0; ks < 4; ++ks) {
                s16x8 bf = *reinterpret_cast<const s16x8*>(&Wu1p[(((nt << 2) + ks) * 64 + lane) * 8]);
                acc = __builtin_amdgcn_mfma_f32_16x16x32_bf16(a1[ks], bf, acc, 0, 0, 0);
            }
            float bias = bu1[nt * 16 + lr];
#pragma unroll
            for (int j = 0; j < 4; ++j) {
                float hh = fmaxf(acc[j] + bias, 0.f);
                Hs[lq * 4 + j][nt * 16 + lr] = f2b(hh);
            }
        }
    }
    __syncthreads();

    // layer 2: Hs @ Wu2 + bu2 -> out
    {
        s16x8 a2[4];
#pragma unroll
        for (int ks = 0; ks < 4; ++ks)
            a2[ks] = *reinterpret_cast<const s16x8*>(&Hs[lr][ks * 32 + lq * 8]);
        f32x4 acc = {0.f, 0.f, 0.f, 0.f};
#pragma unroll
        for (int ks = 0; ks < 4; ++ks) {
            s16x8 bf = *reinterpret_cast<const s16x8*>(&Wu2p[(((wv << 2) + ks) * 64 + lane) * 8]);
            acc = __builtin_amdgcn_mfma_f32_16x16x32_bf16(a2[ks], bf, acc, 0, 0, 0);
        }
        float bias = bu2[wv * 16 + lr];
#pragma unroll
        for (int j = 0; j < 4; ++j)
            out[(size_t)(node0 + lq * 4 + j) * FF + wv * 16 + lr] = acc[j] + bias;
    }
}

// ---------------- legacy fallback (small ws) ----------------

template<int SCALE>
__launch_bounds__(256, 4)
__global__ void node_kernel(const float* __restrict__ node_feats,
                            const float* __restrict__ sums, const float* __restrict__ counts,
                            const unsigned short* __restrict__ W1p, const float* __restrict__ b1,
                            const unsigned short* __restrict__ W2p, const float* __restrict__ b2,
                            float* __restrict__ out) {
    __shared__ unsigned short A1[64][136];
    __shared__ unsigned short Hs[64][136];
    const int tid = threadIdx.x;
    const int g0 = blockIdx.x * 64;
    for (int i = 0; i < 16; ++i) {
        int idx = i * 256 + tid;
        int node = idx >> 6;
        int p = idx & 63;
        int g = g0 + node;
        float2 v;
        if (p < 32) {
            v = *reinterpret_cast<const float2*>(node_feats + (size_t)g * DNF + 2 * p);
        } else {
            float2 s = *reinterpret_cast<const float2*>(sums + (size_t)g * DM + 2 * p - 64);
            if (SCALE) {
                float scale = 1.0f / fmaxf(counts[g], 1.0f);
                s.x *= scale; s.y *= scale;
            }
            v = s;
        }
        unsigned packed = (unsigned)f2b(v.x) | ((unsigned)f2b(v.y) << 16);
        *reinterpret_cast<unsigned*>(&A1[node][2 * p]) = packed;
    }
    __syncthreads();
    const int wave = tid >> 6, lane = tid & 63;
    const int lr = lane & 15, lq = lane >> 4;
    const int arow = wave * 16 + lr;
    s16x8 a[4];
#pragma unroll
    for (int ks = 0; ks < 4; ++ks)
        a[ks] = *reinterpret_cast<const s16x8*>(&A1[arow][ks * 32 + lq * 8]);
#pragma unroll
    for (int nt = 0; nt < 8; ++nt) {
        f32x4 acc = {0.f, 0.f, 0.f, 0.f};
#pragma unroll
        for (int ks = 0; ks < 4; ++ks) {
            s16x8 bf = *reinterpret_cast<const s16x8*>(&W1p[(((nt << 2) + ks) * 64 + lane) * 8]);
            acc = __builtin_amdgcn_mfma_f32_16x16x32_bf16(a[ks], bf, acc, 0, 0, 0);
        }
        float bias = b1[nt * 16 + lr];
#pragma unroll
        for (int j = 0; j < 4; ++j) {
            float h = acc[j] + bias;
            h = h > 0.f ? h : 0.f;
            Hs[wave * 16 + lq * 4 + j][nt * 16 + lr] = f2b(h);
        }
    }
    s16x8 a2[4];
#pragma unroll
    for (int ks = 0; ks < 4; ++ks)
        a2[ks] = *reinterpret_cast<const s16x8*>(&Hs[arow][ks * 32 + lq * 8]);
#pragma unroll
    for (int nt = 0; nt < 4; ++nt) {
        f32x4 acc = {0.f, 0.f, 0.f, 0.f};
#pragma unroll
        for (int ks = 0; ks < 4; ++ks) {
            s16x8 bf = *reinterpret_cast<const s16x8*>(&W2p[(((nt << 2) + ks) * 64 + lane) * 8]);
            acc = __builtin_amdgcn_mfma_f32_16x16x32_bf16(a2[ks], bf, acc, 0, 0, 0);
        }
        float bias = b2[nt * 16 + lr];
#pragma unroll
        for (int j = 0; j < 4; ++j) {
            int g = g0 + wave * 16 + lq * 4 + j;
            out[(size_t)g * FF + nt * 16 + lr] = acc[j] + bias;
        }
    }
}

__launch_bounds__(256, 4)
__global__ void edge_kernel(const float* __restrict__ node_feats,
                            const int* __restrict__ eb, const int* __restrict__ esrc,
                            const int* __restrict__ edst, const float* __restrict__ evals,
                            const unsigned short* __restrict__ W1p, const float* __restrict__ b1,
                            const unsigned short* __restrict__ W2p, const float* __restrict__ b2,
                            float* __restrict__ sums, float* __restrict__ counts) {
    __shared__ unsigned short A1[64][136];
    __shared__ unsigned short Hs[64][136];
    const int tid = threadIdx.x;
    const int e0 = blockIdx.x * 64;
    if (tid < 64) {
        int e = e0 + tid;
        atomicAdd(&counts[eb[e] * NN + esrc[e]], 1.0f);
    }
    for (int i = 0; i < 16; ++i) {
        int idx = i * 256 + tid;
        int edge = idx >> 6;
        int p = idx & 63;
        int e = e0 + edge;
        int b = eb[e];
        const float* row;
        if (p < 32) row = node_feats + ((size_t)b * NN + esrc[e]) * DNF;
        else        row = node_feats + ((size_t)b * NN + edst[e]) * DNF - 64;
        float2 v = *reinterpret_cast<const float2*>(row + 2 * p);
        unsigned packed = (unsigned)f2b(v.x) | ((unsigned)f2b(v.y) << 16);
        *reinterpret_cast<unsigned*>(&A1[edge][2 * p]) = packed;
    }
    __syncthreads();
    const int wave = tid >> 6, lane = tid & 63;
    const int lr = lane & 15, lq = lane >> 4;
    const int arow = wave * 16 + lr;
    s16x8 a[4];
#pragma unroll
    for (int ks = 0; ks < 4; ++ks)
        a[ks] = *reinterpret_cast<const s16x8*>(&A1[arow][ks * 32 + lq * 8]);
#pragma unroll
    for (int nt = 0; nt < 8; ++nt) {
        f32x4 acc = {0.f, 0.f, 0.f, 0.f};
#pragma unroll
        for (int ks = 0; ks < 4; ++ks) {
            s16x8 bf = *reinterpret_cast<const s16x8*>(&W1p[(((nt << 2) + ks) * 64 + lane) * 8]);
            acc = __builtin_amdgcn_mfma_f32_16x16x32_bf16(a[ks], bf, acc, 0, 0, 0);
        }
        float bias = b1[nt * 16 + lr];
#pragma unroll
        for (int j = 0; j < 4; ++j) {
            float h = acc[j] + bias;
            h = h > 0.f ? h : 0.f;
            Hs[wave * 16 + lq * 4 + j][nt * 16 + lr] = f2b(h);
        }
    }
    s16x8 a2[4];
#pragma unroll
    for (int ks = 0; ks < 4; ++ks)
        a2[ks] = *reinterpret_cast<const s16x8*>(&Hs[arow][ks * 32 + lq * 8]);
    float ev[4]; int seg4[4];
#pragma unroll
    for (int j = 0; j < 4; ++j) {
        int r = e0 + wave * 16 + lq * 4 + j;
        ev[j] = evals[r];
        seg4[j] = eb[r] * NN + esrc[r];
    }
#pragma unroll
    for (int nt = 0; nt < 4; ++nt) {
        f32x4 acc = {0.f, 0.f, 0.f, 0.f};
#pragma unroll
        for (int ks = 0; ks < 4; ++ks) {
            s16x8 bf = *reinterpret_cast<const s16x8*>(&W2p[(((nt << 2) + ks) * 64 + lane) * 8]);
            acc = __builtin_amdgcn_mfma_f32_16x16x32_bf16(a2[ks], bf, acc, 0, 0, 0);
        }
        float bias = b2[nt * 16 + lr];
#pragma unroll
        for (int j = 0; j < 4; ++j) {
            float m = (acc[j] + bias) * ev[j];
            atomicAdd(&sums[(size_t)seg4[j] * DM + nt * 16 + lr], m);
        }
    }
}

extern "C" void kernel_launch(void* const* d_in, const int* in_sizes, int n_in,
                              void* d_out, int out_size, void* d_ws, size_t ws_size,
                              hipStream_t stream) {
    const float* node_feats = (const float*)d_in[0];
    const int*   eb    = (const int*)d_in[1];
    const int*   esrc  = (const int*)d_in[2];
    const int*   edst  = (const int*)d_in[3];
    const float* evals = (const float*)d_in[4];
    const float* Wm1 = (const float*)d_in[5];
    const float* bm1 = (const float*)d_in[6];
    const float* Wm2 = (const float*)d_in[7];
    const float* bm2 = (const float*)d_in[8];
    const float* Wu1 = (const float*)d_in[9];
    const float* bu1 = (const float*)d_in[10];
    const float* Wu2 = (const float*)d_in[11];
    const float* bu2 = (const float*)d_in[12];
    float* out = (float*)d_out;
    char* ws = (char*)d_ws;

    const size_t NEED = 29720704;
    if (ws_size >= NEED) {
        unsigned short* Qp      = (unsigned short*)(ws);              // 8 MB
        unsigned short* Pp      = (unsigned short*)(ws + 8388608);    // 8 MB
        unsigned*       payslot = (unsigned*)(ws + 16777216);         // 2048*8*176*4 = 11 MB
        unsigned*       gcurP   = (unsigned*)(ws + 28311552);         // 16384 x 64B = 1 MB
        unsigned*       ovf_cnt = (unsigned*)(ws + 29360128);         // 128 B
        unsigned*       ovf_seg = (unsigned*)(ws + 29360256);         // 128 KB
        unsigned*       ovf_pay = (unsigned*)(ws + 29491328);         // 128 KB
        unsigned short* Qw      = (unsigned short*)(ws + 29622400);   // 16 KB
        unsigned short* Pw      = (unsigned short*)(ws + 29638784);   // 16 KB
        unsigned short* Wu1p    = (unsigned short*)(ws + 29655168);   // 32 KB
        unsigned short* Wu2p    = (unsigned short*)(ws + 29687936);   // 16 KB
        unsigned short* Wm2p    = (unsigned short*)(ws + 29704320);   // 16 KB

        hipMemsetAsync(gcurP, 0, 1048576 + 128, stream);   // gcurP + ovf_cnt contiguous
        pack_all<<<192, 256, 0, stream>>>(Wm1, Wm2, Wu1, Wu2, Qw, Pw, Wm2p, Wu1p, Wu2p);
        precompute_pq<<<512, 256, 0, stream>>>(node_feats, Qw, Pw, bm1, Qp, Pp);
        scatter_xcd<<<NEDGE / 1024, 256, 0, stream>>>(eb, esrc, edst, evals,
                                                      gcurP, payslot, ovf_cnt, ovf_seg, ovf_pay);
        bucket16_fused<<<NBKT2, 256, 0, stream>>>(Qp, Pp, payslot, gcurP,
                                                  ovf_cnt, ovf_seg, ovf_pay,
                                                  Wm2p, bm2, node_feats,
                                                  Wu1p, bu1, Wu2p, bu2, out);
    } else {
        float* counts          = (float*)ws;
        unsigned short* W1p    = (unsigned short*)(ws + 131072);
        unsigned short* W2p    = (unsigned short*)(ws + 163840);
        unsigned short* Wu1p   = (unsigned short*)(ws + 180224);
        unsigned short* Wu2p   = (unsigned short*)(ws + 212992);
        hipMemsetAsync(d_out, 0, (size_t)out_size * sizeof(float), stream);
        hipMemsetAsync(counts, 0, 32768 * sizeof(float), stream);
        pack_weights<<<64, 256, 0, stream>>>(Wm1, W1p, 128, 128);
        pack_weights<<<32, 256, 0, stream>>>(Wm2, W2p, 128, 64);
        pack_weights<<<64, 256, 0, stream>>>(Wu1, Wu1p, 128, 128);
        pack_weights<<<32, 256, 0, stream>>>(Wu2, Wu2p, 128, 64);
        edge_kernel<<<NEDGE / 64, 256, 0, stream>>>(node_feats, eb, esrc, edst, evals,
                                                    W1p, bm1, W2p, bm2, out, counts);
        node_kernel<1><<<(NB * NN) / 64, 256, 0, stream>>>(node_feats, out, counts,
                                                           Wu1p, bu1, Wu2p, bu2, out);
    }
}

// Round 11
// 111.327 us; speedup vs baseline: 1.2002x; 1.0680x over previous
//
#include <hip/hip_runtime.h>

#define NB 8
#define NN 4096
#define DNF 64
#define NEDGE 1048576
#define DM 64
#define FF 64

#define NBKT2 2048        // buckets (seg>>4)
#define SPB2 16           // segments per bucket
#define NXCD 8
#define SUBCAP 176        // slots per (bucket,xcd): mean 64, +15 sigma
#define OVFCAP 32768
#define SCATBLK 2048      // scatter blocks in merged kernel

using f32x4 = __attribute__((ext_vector_type(4))) float;
using f32x2 = __attribute__((ext_vector_type(2))) float;
using s16x8 = __attribute__((ext_vector_type(8))) short;

__device__ __forceinline__ unsigned short f2b(float f) {
    union { float f; unsigned u; } v; v.f = f;
    unsigned r = (v.u + 0x7fffu + ((v.u >> 16) & 1u)) >> 16;
    return (unsigned short)r;
}
__device__ __forceinline__ float uif(unsigned u) {
    union { unsigned u; float f; } v; v.u = u;
    return v.f;
}

// Pack W [K x Ncols] (f32 row-major) into MFMA B-fragment order (bf16)
__device__ __forceinline__ void pack_one(const float* __restrict__ W,
                                         unsigned short* __restrict__ out,
                                         int K, int Ncols, int idx) {
    int j = idx & 7;
    int lane = (idx >> 3) & 63;
    int frag = idx >> 9;
    int KS = K >> 5;
    int ks = frag % KS;
    int nt = frag / KS;
    int k = ks * 32 + ((lane >> 4) << 3) + j;
    int col = nt * 16 + (lane & 15);
    out[idx] = f2b(W[k * Ncols + col]);
}

__global__ void pack_all(const float* __restrict__ Wm1, const float* __restrict__ Wm2,
                         const float* __restrict__ Wu1, const float* __restrict__ Wu2,
                         unsigned short* __restrict__ Qw, unsigned short* __restrict__ Pw,
                         unsigned short* __restrict__ Wm2p,
                         unsigned short* __restrict__ Wu1p, unsigned short* __restrict__ Wu2p) {
    int idx = blockIdx.x * 256 + threadIdx.x;
    if (idx < 8192)        pack_one(Wm1,              Qw,   64, 128, idx);
    else if (idx < 16384)  pack_one(Wm1 + 64 * 128,   Pw,   64, 128, idx - 8192);
    else if (idx < 24576)  pack_one(Wm2,              Wm2p, 128, 64, idx - 16384);
    else if (idx < 40960)  pack_one(Wu1,              Wu1p, 128, 128, idx - 24576);
    else                   pack_one(Wu2,              Wu2p, 128, 64, idx - 40960);
}

__global__ void pack_weights(const float* __restrict__ W, unsigned short* __restrict__ out,
                             int K, int Ncols) {
    int idx = blockIdx.x * 256 + threadIdx.x;
    if (idx >= K * Ncols) return;
    pack_one(W, out, K, Ncols, idx);
}

// Merged kernel: blocks [0, SCATBLK) do the edge scatter (latency-bound);
// blocks [SCATBLK, SCATBLK+512) do precompute_pq (MFMA-bound). Independent work.
__launch_bounds__(256, 6)
__global__ void scatter_pq(const int* __restrict__ eb, const int* __restrict__ esrc,
                           const int* __restrict__ edst, const float* __restrict__ evals,
                           unsigned* __restrict__ gcurP, unsigned* __restrict__ payslot,
                           unsigned* __restrict__ ovf_cnt, unsigned* __restrict__ ovf_seg,
                           unsigned* __restrict__ ovf_pay,
                           const float* __restrict__ X,
                           const unsigned short* __restrict__ Qw,
                           const unsigned short* __restrict__ Pw,
                           const float* __restrict__ b1,
                           unsigned short* __restrict__ Qp,
                           unsigned short* __restrict__ Pp) {
    __shared__ unsigned short A[64][72];
    if (blockIdx.x < SCATBLK) {
        // ---- scatter: 2 edges/thread, per-(bucket,XCD) padded counters ----
        unsigned xcd;
        asm volatile("s_getreg_b32 %0, hwreg(HW_REG_XCC_ID)" : "=s"(xcd));
        xcd &= (NXCD - 1);
        const int t0 = blockIdx.x * 512 + threadIdx.x;
        int seg[2]; unsigned pk[2];
#pragma unroll
        for (int k = 0; k < 2; ++k) {
            int e = t0 + k * 256;
            seg[k] = eb[e] * NN + esrc[e];
            unsigned wq = (unsigned)fminf(evals[e] * 8192.0f + 0.5f, 8191.0f);
            pk[k] = (unsigned)edst[e] | (wq << 12) | ((unsigned)(seg[k] & 15) << 25);
        }
        unsigned pos[2];
#pragma unroll
        for (int k = 0; k < 2; ++k)
            pos[k] = atomicAdd(&gcurP[((int)xcd * NBKT2 + (seg[k] >> 4)) * 16], 1u);
#pragma unroll
        for (int k = 0; k < 2; ++k) {
            if (pos[k] < (unsigned)SUBCAP) {
                payslot[((size_t)(seg[k] >> 4) * NXCD + xcd) * SUBCAP + pos[k]] = pk[k];
            } else {
                unsigned o = atomicAdd(ovf_cnt, 1u);
                if (o < (unsigned)OVFCAP) { ovf_seg[o] = (unsigned)seg[k]; ovf_pay[o] = pk[k]; }
            }
        }
    } else {
        // ---- precompute_pq: Q = X@Wm1[:64]+b1 (folded), P = X@Wm1[64:] ----
        const int tid = threadIdx.x;
        const int g0 = (blockIdx.x - SCATBLK) * 64;
        for (int i = 0; i < 16; ++i) {
            int idx = i * 256 + tid;
            int node = idx >> 6;
            int f = idx & 63;
            A[node][f] = f2b(X[(size_t)(g0 + node) * DNF + f]);
        }
        __syncthreads();
        const int wave = tid >> 6, lane = tid & 63;
        const int lr = lane & 15, lq = lane >> 4;
        const int arow = wave * 16 + lr;
        s16x8 a[2];
#pragma unroll
        for (int ks = 0; ks < 2; ++ks)
            a[ks] = *reinterpret_cast<const s16x8*>(&A[arow][ks * 32 + lq * 8]);
#pragma unroll
        for (int nt = 0; nt < 8; ++nt) {
            f32x4 accQ = {0.f, 0.f, 0.f, 0.f};
            f32x4 accP = {0.f, 0.f, 0.f, 0.f};
#pragma unroll
            for (int ks = 0; ks < 2; ++ks) {
                s16x8 bq = *reinterpret_cast<const s16x8*>(&Qw[(((nt << 1) + ks) * 64 + lane) * 8]);
                s16x8 bp = *reinterpret_cast<const s16x8*>(&Pw[(((nt << 1) + ks) * 64 + lane) * 8]);
                accQ = __builtin_amdgcn_mfma_f32_16x16x32_bf16(a[ks], bq, accQ, 0, 0, 0);
                accP = __builtin_amdgcn_mfma_f32_16x16x32_bf16(a[ks], bp, accP, 0, 0, 0);
            }
            int col = nt * 16 + lr;
            float bias = b1[col];
#pragma unroll
            for (int j = 0; j < 4; ++j) {
                int row = g0 + wave * 16 + lq * 4 + j;
                Qp[(size_t)row * 128 + col] = f2b(accQ[j] + bias);
                Pp[(size_t)row * 128 + col] = f2b(accP[j]);
            }
        }
    }
}

// Pass B: one bucket (16 segments = 16 consecutive nodes) per block.
// Scalarized reduce: wave-uniform payload -> readfirstlane -> SALU decode/addr,
// SADDR P-loads, packed-f32 (v_pk) math, 2^-13 weight scale folded into SC.
__launch_bounds__(256, 6)
__global__ void bucket16_fused(const unsigned short* __restrict__ Qp,
                               const unsigned short* __restrict__ Pp,
                               const unsigned* __restrict__ payslot,
                               const unsigned* __restrict__ gcurP,
                               const unsigned* __restrict__ ovf_cnt,
                               const unsigned* __restrict__ ovf_seg,
                               const unsigned* __restrict__ ovf_pay,
                               const unsigned short* __restrict__ Wm2p,
                               const float* __restrict__ b2m,
                               const float* __restrict__ X,
                               const unsigned short* __restrict__ Wu1p,
                               const float* __restrict__ bu1,
                               const unsigned short* __restrict__ Wu2p,
                               const float* __restrict__ bu2,
                               float* __restrict__ out) {
    __shared__ unsigned raw[NXCD * SUBCAP];
    __shared__ unsigned sorted[NXCD * SUBCAP];
    __shared__ unsigned short S[16][136];
    __shared__ unsigned short A1[16][136];
    __shared__ unsigned short Hs[16][136];
    __shared__ unsigned h4[4][16];
    __shared__ unsigned curb4[4][16];
    __shared__ unsigned offs[17];
    __shared__ unsigned cx[NXCD];
    __shared__ float SW[16], SC[16];
    const int tid = threadIdx.x, wv = tid >> 6, lane = tid & 63;
    // XCD-affine swizzle: blocks round-robin XCDs; give XCD x the buckets of batch x.
    const int bkt = (blockIdx.x & 7) * 256 + (blockIdx.x >> 3);
    const int node0 = bkt * SPB2;                 // first seg == first node id
    const int rowbase = (bkt >> 8) << 12;         // batch * NN
    const unsigned novf = ovf_cnt[0];

    // stage node feats into A1[:, 0:64]
#pragma unroll
    for (int i = 0; i < 4; ++i) {
        int idx = i * 256 + tid;
        int row = idx >> 6, f = idx & 63;
        A1[row][f] = f2b(X[(size_t)(node0 + row) * DNF + f]);
    }
    if (tid < 64) ((unsigned*)h4)[tid] = 0;
    if (tid < NXCD) cx[tid] = min(gcurP[(tid * NBKT2 + bkt) * 16], (unsigned)SUBCAP);
    __syncthreads();
    // load + per-wave hist: wave w owns sub-lists 2w, 2w+1
#pragma unroll
    for (int xi = 0; xi < 2; ++xi) {
        int x = wv * 2 + xi;
        unsigned c = cx[x];
        for (unsigned i = lane; i < c; i += 64) {
            unsigned v = payslot[((size_t)bkt * NXCD + x) * SUBCAP + i];
            raw[x * SUBCAP + i] = v;
            atomicAdd(&h4[wv][(v >> 25) & 15u], 1u);
        }
    }
    __syncthreads();
    if (tid < 16) {                                // 16-bin scan of summed hist
        int xx = (int)(h4[0][tid] + h4[1][tid] + h4[2][tid] + h4[3][tid]);
#pragma unroll
        for (int o = 1; o < 16; o <<= 1) {
            int y = __shfl_up(xx, o);
            if (tid >= o) xx += y;
        }
        offs[tid + 1] = (unsigned)xx;
        if (tid == 0) offs[0] = 0;
    }
    __syncthreads();
    if (tid < 64) {                                // per-(wave,bin) disjoint cursors
        int w = tid >> 4, b = tid & 15;
        unsigned base = offs[b];
        for (int w2 = 0; w2 < w; ++w2) base += h4[w2][b];
        curb4[w][b] = base;
    }
    __syncthreads();
#pragma unroll
    for (int xi = 0; xi < 2; ++xi) {               // LDS->LDS reorder, per-wave cursors
        int x = wv * 2 + xi;
        unsigned c = cx[x];
        for (unsigned i = lane; i < c; i += 64) {
            unsigned v = raw[x * SUBCAP + i];
            unsigned pos = atomicAdd(&curb4[wv][(v >> 25) & 15u], 1u);
            sorted[pos] = v;
        }
    }
    __syncthreads();

    const unsigned* P32 = reinterpret_cast<const unsigned*>(Pp);
    const unsigned* Q32 = reinterpret_cast<const unsigned*>(Qp);
    const unsigned* PbS = P32 + (size_t)rowbase * 64;   // block-uniform base
    for (int si = 0; si < 4; ++si) {
        const int lo = wv * 4 + si;
        const int seg = node0 + lo;
        const unsigned s0 = offs[lo], s1 = offs[lo + 1];
        unsigned qv = Q32[(size_t)seg * 64 + lane];
        f32x2 q2 = { uif(qv << 16), uif(qv & 0xffff0000u) };
        f32x2 acc2 = { 0.f, 0.f };
        unsigned scnt = s1 - s0;

        // lane-parallel weight sum (integer-valued; 2^-13 folded into SC)
        float wl = 0.f;
        for (unsigned i = s0 + lane; i < s1; i += 64)
            wl += (float)((sorted[i] >> 12) & 8191u);
        for (int m2 = 1; m2 < 64; m2 <<= 1) wl += __shfl_xor(wl, m2);
        float wsum = wl;

        for (unsigned bse = s0; bse < s1; bse += 8) {
            unsigned pv[8]; float wf[8];
#pragma unroll
            for (int k = 0; k < 8; ++k) {
                unsigned idx = bse + (unsigned)k;
                unsigned cu = (idx < s1) ? sorted[idx] : 0u;  // wave-uniform
                int ci = __builtin_amdgcn_readfirstlane((int)cu);
                wf[k] = (float)(unsigned)((ci >> 12) & 8191); // integer-valued weight
                int row = ci & 0xfff;                          // scalar P row
                pv[k] = PbS[(size_t)row * 64 + lane];          // SADDR-form load
            }
#pragma unroll
            for (int k = 0; k < 8; ++k) {
                f32x2 p2 = { uif(pv[k] << 16), uif(pv[k] & 0xffff0000u) };
                f32x2 h2 = q2 + p2;                            // v_pk_add_f32
                h2 = __builtin_elementwise_max(h2, (f32x2){0.f, 0.f});
                acc2 += wf[k] * h2;                            // v_pk_fma_f32
            }
        }
        if (novf > 0) {                            // normally empty, guaranteed-correct
            unsigned ncl = min(novf, (unsigned)OVFCAP);
            for (unsigned i = 0; i < ncl; ++i) {
                if (ovf_seg[i] == (unsigned)seg) {
                    unsigned c = ovf_pay[i];
                    float w = (float)((c >> 12) & 8191u);
                    unsigned pv = PbS[(size_t)(c & 0xfffu) * 64 + lane];
                    f32x2 p2 = { uif(pv << 16), uif(pv & 0xffff0000u) };
                    f32x2 h2 = q2 + p2;
                    h2 = __builtin_elementwise_max(h2, (f32x2){0.f, 0.f});
                    acc2 += w * h2;
                    wsum += w;
                    scnt += 1;
                }
            }
        }
        unsigned sp = (unsigned)f2b(acc2.x) | ((unsigned)f2b(acc2.y) << 16);
        *reinterpret_cast<unsigned*>(&S[lo][2 * lane]) = sp;
        if (lane == 0) {
            SW[lo] = wsum;
            SC[lo] = (1.0f / 8192.0f) / (float)max(scnt, 1u);  // scale fold (exact pow2)
        }
    }
    __syncthreads();

    const int lr = lane & 15, lq = lane >> 4;
    // gathered = (S @ Wm2 + sumw*b2) * SC -> A1[:, 64:128] (bf16)
    {
        s16x8 a[4];
#pragma unroll
        for (int ks = 0; ks < 4; ++ks)
            a[ks] = *reinterpret_cast<const s16x8*>(&S[lr][ks * 32 + lq * 8]);
        f32x4 acc = {0.f, 0.f, 0.f, 0.f};
#pragma unroll
        for (int ks = 0; ks < 4; ++ks) {
            s16x8 bf = *reinterpret_cast<const s16x8*>(&Wm2p[(((wv << 2) + ks) * 64 + lane) * 8]);
            acc = __builtin_amdgcn_mfma_f32_16x16x32_bf16(a[ks], bf, acc, 0, 0, 0);
        }
        float bb = b2m[wv * 16 + lr];
#pragma unroll
        for (int j = 0; j < 4; ++j) {
            int r = lq * 4 + j;
            float g = (acc[j] + SW[r] * bb) * SC[r];
            A1[r][64 + wv * 16 + lr] = f2b(g);
        }
    }
    __syncthreads();

    // node MLP layer 1: relu([X|gathered] @ Wu1 + bu1) -> Hs
    {
        s16x8 a1[4];
#pragma unroll
        for (int ks = 0; ks < 4; ++ks)
            a1[ks] = *reinterpret_cast<const s16x8*>(&A1[lr][ks * 32 + lq * 8]);
#pragma unroll
        for (int t = 0; t < 2; ++t) {
            int nt = wv * 2 + t;
            f32x4 acc = {0.f, 0.f, 0.f, 0.f};
#pragma unroll
            for (int ks = 0; ks < 4; ++ks) {
                s16x8 bf = *reinterpret_cast<const s16x8*>(&Wu1p[(((nt << 2) + ks) * 64 + lane) * 8]);
                acc = __builtin_amdgcn_mfma_f32_16x16x32_bf16(a1[ks], bf, acc, 0, 0, 0);
            }
            float bias = bu1[nt * 16 + lr];
#pragma unroll
            for (int j = 0; j < 4; ++j) {
                float hh = fmaxf(acc[j] + bias, 0.f);
                Hs[lq * 4 + j][nt * 16 + lr] = f2b(hh);
            }
        }
    }
    __syncthreads();

    // layer 2: Hs @ Wu2 + bu2 -> out
    {
        s16x8 a2[4];
#pragma unroll
        for (int ks = 0; ks < 4; ++ks)
            a2[ks] = *reinterpret_cast<const s16x8*>(&Hs[lr][ks * 32 + lq * 8]);
        f32x4 acc = {0.f, 0.f, 0.f, 0.f};
#pragma unroll
        for (int ks = 0; ks < 4; ++ks) {
            s16x8 bf = *reinterpret_cast<const s16x8*>(&Wu2p[(((wv << 2) + ks) * 64 + lane) * 8]);
            acc = __builtin_amdgcn_mfma_f32_16x16x32_bf16(a2[ks], bf, acc, 0, 0, 0);
        }
        float bias = bu2[wv * 16 + lr];
#pragma unroll
        for (int j = 0; j < 4; ++j)
            out[(size_t)(node0 + lq * 4 + j) * FF + wv * 16 + lr] = acc[j] + bias;
    }
}

// ---------------- legacy fallback (small ws) ----------------

template<int SCALE>
__launch_bounds__(256, 4)
__global__ void node_kernel(const float* __restrict__ node_feats,
                            const float* __restrict__ sums, const float* __restrict__ counts,
                            const unsigned short* __restrict__ W1p, const float* __restrict__ b1,
                            const unsigned short* __restrict__ W2p, const float* __restrict__ b2,
                            float* __restrict__ out) {
    __shared__ unsigned short A1[64][136];
    __shared__ unsigned short Hs[64][136];
    const int tid = threadIdx.x;
    const int g0 = blockIdx.x * 64;
    for (int i = 0; i < 16; ++i) {
        int idx = i * 256 + tid;
        int node = idx >> 6;
        int p = idx & 63;
        int g = g0 + node;
        float2 v;
        if (p < 32) {
            v = *reinterpret_cast<const float2*>(node_feats + (size_t)g * DNF + 2 * p);
        } else {
            float2 s = *reinterpret_cast<const float2*>(sums + (size_t)g * DM + 2 * p - 64);
            if (SCALE) {
                float scale = 1.0f / fmaxf(counts[g], 1.0f);
                s.x *= scale; s.y *= scale;
            }
            v = s;
        }
        unsigned packed = (unsigned)f2b(v.x) | ((unsigned)f2b(v.y) << 16);
        *reinterpret_cast<unsigned*>(&A1[node][2 * p]) = packed;
    }
    __syncthreads();
    const int wave = tid >> 6, lane = tid & 63;
    const int lr = lane & 15, lq = lane >> 4;
    const int arow = wave * 16 + lr;
    s16x8 a[4];
#pragma unroll
    for (int ks = 0; ks < 4; ++ks)
        a[ks] = *reinterpret_cast<const s16x8*>(&A1[arow][ks * 32 + lq * 8]);
#pragma unroll
    for (int nt = 0; nt < 8; ++nt) {
        f32x4 acc = {0.f, 0.f, 0.f, 0.f};
#pragma unroll
        for (int ks = 0; ks < 4; ++ks) {
            s16x8 bf = *reinterpret_cast<const s16x8*>(&W1p[(((nt << 2) + ks) * 64 + lane) * 8]);
            acc = __builtin_amdgcn_mfma_f32_16x16x32_bf16(a[ks], bf, acc, 0, 0, 0);
        }
        float bias = b1[nt * 16 + lr];
#pragma unroll
        for (int j = 0; j < 4; ++j) {
            float h = acc[j] + bias;
            h = h > 0.f ? h : 0.f;
            Hs[wave * 16 + lq * 4 + j][nt * 16 + lr] = f2b(h);
        }
    }
    s16x8 a2[4];
#pragma unroll
    for (int ks = 0; ks < 4; ++ks)
        a2[ks] = *reinterpret_cast<const s16x8*>(&Hs[arow][ks * 32 + lq * 8]);
#pragma unroll
    for (int nt = 0; nt < 4; ++nt) {
        f32x4 acc = {0.f, 0.f, 0.f, 0.f};
#pragma unroll
        for (int ks = 0; ks < 4; ++ks) {
            s16x8 bf = *reinterpret_cast<const s16x8*>(&W2p[(((nt << 2) + ks) * 64 + lane) * 8]);
            acc = __builtin_amdgcn_mfma_f32_16x16x32_bf16(a2[ks], bf, acc, 0, 0, 0);
        }
        float bias = b2[nt * 16 + lr];
#pragma unroll
        for (int j = 0; j < 4; ++j) {
            int g = g0 + wave * 16 + lq * 4 + j;
            out[(size_t)g * FF + nt * 16 + lr] = acc[j] + bias;
        }
    }
}

__launch_bounds__(256, 4)
__global__ void edge_kernel(const float* __restrict__ node_feats,
                            const int* __restrict__ eb, const int* __restrict__ esrc,
                            const int* __restrict__ edst, const float* __restrict__ evals,
                            const unsigned short* __restrict__ W1p, const float* __restrict__ b1,
                            const unsigned short* __restrict__ W2p, const float* __restrict__ b2,
                            float* __restrict__ sums, float* __restrict__ counts) {
    __shared__ unsigned short A1[64][136];
    __shared__ unsigned short Hs[64][136];
    const int tid = threadIdx.x;
    const int e0 = blockIdx.x * 64;
    if (tid < 64) {
        int e = e0 + tid;
        atomicAdd(&counts[eb[e] * NN + esrc[e]], 1.0f);
    }
    for (int i = 0; i < 16; ++i) {
        int idx = i * 256 + tid;
        int edge = idx >> 6;
        int p = idx & 63;
        int e = e0 + edge;
        int b = eb[e];
        const float* row;
        if (p < 32) row = node_feats + ((size_t)b * NN + esrc[e]) * DNF;
        else        row = node_feats + ((size_t)b * NN + edst[e]) * DNF - 64;
        float2 v = *reinterpret_cast<const float2*>(row + 2 * p);
        unsigned packed = (unsigned)f2b(v.x) | ((unsigned)f2b(v.y) << 16);
        *reinterpret_cast<unsigned*>(&A1[edge][2 * p]) = packed;
    }
    __syncthreads();
    const int wave = tid >> 6, lane = tid & 63;
    const int lr = lane & 15, lq = lane >> 4;
    const int arow = wave * 16 + lr;
    s16x8 a[4];
#pragma unroll
    for (int ks = 0; ks < 4; ++ks)
        a[ks] = *reinterpret_cast<const s16x8*>(&A1[arow][ks * 32 + lq * 8]);
#pragma unroll
    for (int nt = 0; nt < 8; ++nt) {
        f32x4 acc = {0.f, 0.f, 0.f, 0.f};
#pragma unroll
        for (int ks = 0; ks < 4; ++ks) {
            s16x8 bf = *reinterpret_cast<const s16x8*>(&W1p[(((nt << 2) + ks) * 64 + lane) * 8]);
            acc = __builtin_amdgcn_mfma_f32_16x16x32_bf16(a[ks], bf, acc, 0, 0, 0);
        }
        float bias = b1[nt * 16 + lr];
#pragma unroll
        for (int j = 0; j < 4; ++j) {
            float h = acc[j] + bias;
            h = h > 0.f ? h : 0.f;
            Hs[wave * 16 + lq * 4 + j][nt * 16 + lr] = f2b(h);
        }
    }
    s16x8 a2[4];
#pragma unroll
    for (int ks = 0; ks < 4; ++ks)
        a2[ks] = *reinterpret_cast<const s16x8*>(&Hs[arow][ks * 32 + lq * 8]);
    float ev[4]; int seg4[4];
#pragma unroll
    for (int j = 0; j < 4; ++j) {
        int r = e0 + wave * 16 + lq * 4 + j;
        ev[j] = evals[r];
        seg4[j] = eb[r] * NN + esrc[r];
    }
#pragma unroll
    for (int nt = 0; nt < 4; ++nt) {
        f32x4 acc = {0.f, 0.f, 0.f, 0.f};
#pragma unroll
        for (int ks = 0; ks < 4; ++ks) {
            s16x8 bf = *reinterpret_cast<const s16x8*>(&W2p[(((nt << 2) + ks) * 64 + lane) * 8]);
            acc = __builtin_amdgcn_mfma_f32_16x16x32_bf16(a2[ks], bf, acc, 0, 0, 0);
        }
        float bias = b2[nt * 16 + lr];
#pragma unroll
        for (int j = 0; j < 4; ++j) {
            float m = (acc[j] + bias) * ev[j];
            atomicAdd(&sums[(size_t)seg4[j] * DM + nt * 16 + lr], m);
        }
    }
}

extern "C" void kernel_launch(void* const* d_in, const int* in_sizes, int n_in,
                              void* d_out, int out_size, void* d_ws, size_t ws_size,
                              hipStream_t stream) {
    const float* node_feats = (const float*)d_in[0];
    const int*   eb    = (const int*)d_in[1];
    const int*   esrc  = (const int*)d_in[2];
    const int*   edst  = (const int*)d_in[3];
    const float* evals = (const float*)d_in[4];
    const float* Wm1 = (const float*)d_in[5];
    const float* bm1 = (const float*)d_in[6];
    const float* Wm2 = (const float*)d_in[7];
    const float* bm2 = (const float*)d_in[8];
    const float* Wu1 = (const float*)d_in[9];
    const float* bu1 = (const float*)d_in[10];
    const float* Wu2 = (const float*)d_in[11];
    const float* bu2 = (const float*)d_in[12];
    float* out = (float*)d_out;
    char* ws = (char*)d_ws;

    const size_t NEED = 29720704;
    if (ws_size >= NEED) {
        unsigned short* Qp      = (unsigned short*)(ws);              // 8 MB
        unsigned short* Pp      = (unsigned short*)(ws + 8388608);    // 8 MB
        unsigned*       payslot = (unsigned*)(ws + 16777216);         // 2048*8*176*4 = 11 MB
        unsigned*       gcurP   = (unsigned*)(ws + 28311552);         // 16384 x 64B = 1 MB
        unsigned*       ovf_cnt = (unsigned*)(ws + 29360128);         // 128 B
        unsigned*       ovf_seg = (unsigned*)(ws + 29360256);         // 128 KB
        unsigned*       ovf_pay = (unsigned*)(ws + 29491328);         // 128 KB
        unsigned short* Qw      = (unsigned short*)(ws + 29622400);   // 16 KB
        unsigned short* Pw      = (unsigned short*)(ws + 29638784);   // 16 KB
        unsigned short* Wu1p    = (unsigned short*)(ws + 29655168);   // 32 KB
        unsigned short* Wu2p    = (unsigned short*)(ws + 29687936);   // 16 KB
        unsigned short* Wm2p    = (unsigned short*)(ws + 29704320);   // 16 KB

        hipMemsetAsync(gcurP, 0, 1048576 + 128, stream);   // gcurP + ovf_cnt contiguous
        pack_all<<<192, 256, 0, stream>>>(Wm1, Wm2, Wu1, Wu2, Qw, Pw, Wm2p, Wu1p, Wu2p);
        scatter_pq<<<SCATBLK + 512, 256, 0, stream>>>(eb, esrc, edst, evals,
                                                      gcurP, payslot, ovf_cnt, ovf_seg, ovf_pay,
                                                      node_feats, Qw, Pw, bm1, Qp, Pp);
        bucket16_fused<<<NBKT2, 256, 0, stream>>>(Qp, Pp, payslot, gcurP,
                                                  ovf_cnt, ovf_seg, ovf_pay,
                                                  Wm2p, bm2, node_feats,
                                                  Wu1p, bu1, Wu2p, bu2, out);
    } else {
        float* counts          = (float*)ws;
        unsigned short* W1p    = (unsigned short*)(ws + 131072);
        unsigned short* W2p    = (unsigned short*)(ws + 163840);
        unsigned short* Wu1p   = (unsigned short*)(ws + 180224);
        unsigned short* Wu2p   = (unsigned short*)(ws + 212992);
        hipMemsetAsync(d_out, 0, (size_t)out_size * sizeof(float), stream);
        hipMemsetAsync(counts, 0, 32768 * sizeof(float), stream);
        pack_weights<<<64, 256, 0, stream>>>(Wm1, W1p, 128, 128);
        pack_weights<<<32, 256, 0, stream>>>(Wm2, W2p, 128, 64);
        pack_weights<<<64, 256, 0, stream>>>(Wu1, Wu1p, 128, 128);
        pack_weights<<<32, 256, 0, stream>>>(Wu2, Wu2p, 128, 64);
        edge_kernel<<<NEDGE / 64, 256, 0, stream>>>(node_feats, eb, esrc, edst, evals,
                                                    W1p, bm1, W2p, bm2, out, counts);
        node_kernel<1><<<(NB * NN) / 64, 256, 0, stream>>>(node_feats, out, counts,
                                                           Wu1p, bu1, Wu2p, bu2, out);
    }
}

// Round 12
// 101.935 us; speedup vs baseline: 1.3108x; 1.0921x over previous
//
#include <hip/hip_runtime.h>

#define NB 8
#define NN 4096
#define DNF 64
#define NEDGE 1048576
#define DM 64
#define FF 64

#define NBKT2 2048        // buckets (seg>>4)
#define SPB2 16           // segments per bucket
#define SORTBLK 512       // blocks in hist/sort passes
#define EPB 2048          // edges per sort block
#define CHUNK 1024        // Pass-B LDS chunk

using f32x4 = __attribute__((ext_vector_type(4))) float;
using f32x2 = __attribute__((ext_vector_type(2))) float;
using s16x8 = __attribute__((ext_vector_type(8))) short;

__device__ __forceinline__ unsigned short f2b(float f) {
    union { float f; unsigned u; } v; v.f = f;
    unsigned r = (v.u + 0x7fffu + ((v.u >> 16) & 1u)) >> 16;
    return (unsigned short)r;
}
__device__ __forceinline__ float uif(unsigned u) {
    union { unsigned u; float f; } v; v.u = u;
    return v.f;
}

// Pack W [K x Ncols] (f32 row-major) into MFMA B-fragment order (bf16)
__device__ __forceinline__ void pack_one(const float* __restrict__ W,
                                         unsigned short* __restrict__ out,
                                         int K, int Ncols, int idx) {
    int j = idx & 7;
    int lane = (idx >> 3) & 63;
    int frag = idx >> 9;
    int KS = K >> 5;
    int ks = frag % KS;
    int nt = frag / KS;
    int k = ks * 32 + ((lane >> 4) << 3) + j;
    int col = nt * 16 + (lane & 15);
    out[idx] = f2b(W[k * Ncols + col]);
}

__global__ void pack_all(const float* __restrict__ Wm1, const float* __restrict__ Wm2,
                         const float* __restrict__ Wu1, const float* __restrict__ Wu2,
                         unsigned short* __restrict__ Qw, unsigned short* __restrict__ Pw,
                         unsigned short* __restrict__ Wm2p,
                         unsigned short* __restrict__ Wu1p, unsigned short* __restrict__ Wu2p) {
    int idx = blockIdx.x * 256 + threadIdx.x;
    if (idx < 8192)        pack_one(Wm1,              Qw,   64, 128, idx);
    else if (idx < 16384)  pack_one(Wm1 + 64 * 128,   Pw,   64, 128, idx - 8192);
    else if (idx < 24576)  pack_one(Wm2,              Wm2p, 128, 64, idx - 16384);
    else if (idx < 40960)  pack_one(Wu1,              Wu1p, 128, 128, idx - 24576);
    else                   pack_one(Wu2,              Wu2p, 128, 64, idx - 40960);
}

__global__ void pack_weights(const float* __restrict__ W, unsigned short* __restrict__ out,
                             int K, int Ncols) {
    int idx = blockIdx.x * 256 + threadIdx.x;
    if (idx >= K * Ncols) return;
    pack_one(W, out, K, Ncols, idx);
}

// K1: blocks [0,512) = per-block 2048-bucket histogram (coalesced row write);
//     blocks [512,1024) = precompute Q/P (Q = X@Wm1[:64]+b1 folded, P = X@Wm1[64:]).
__launch_bounds__(256, 8)
__global__ void hist_pq(const int* __restrict__ eb, const int* __restrict__ esrc,
                        unsigned* __restrict__ histm,
                        const float* __restrict__ X,
                        const unsigned short* __restrict__ Qw,
                        const unsigned short* __restrict__ Pw,
                        const float* __restrict__ b1,
                        unsigned short* __restrict__ Qp,
                        unsigned short* __restrict__ Pp) {
    __shared__ unsigned lds_u[2304];     // 9216B: bins[2048] | A[64][72] bf16
    const int tid = threadIdx.x;
    if (blockIdx.x < SORTBLK) {
        unsigned* bins = lds_u;
        for (int i = tid; i < NBKT2; i += 256) bins[i] = 0;
        __syncthreads();
        const int e0 = blockIdx.x * EPB;
#pragma unroll
        for (int i = 0; i < EPB / 256; ++i) {
            int e = e0 + i * 256 + tid;
            atomicAdd(&bins[(eb[e] * NN + esrc[e]) >> 4], 1u);
        }
        __syncthreads();
        for (int i = tid; i < NBKT2; i += 256)
            histm[(size_t)blockIdx.x * NBKT2 + i] = bins[i];
    } else {
        unsigned short (*A)[72] = reinterpret_cast<unsigned short(*)[72]>(lds_u);
        const int g0 = (blockIdx.x - SORTBLK) * 64;
        for (int i = 0; i < 16; ++i) {
            int idx = i * 256 + tid;
            int node = idx >> 6;
            int f = idx & 63;
            A[node][f] = f2b(X[(size_t)(g0 + node) * DNF + f]);
        }
        __syncthreads();
        const int wave = tid >> 6, lane = tid & 63;
        const int lr = lane & 15, lq = lane >> 4;
        const int arow = wave * 16 + lr;
        s16x8 a[2];
#pragma unroll
        for (int ks = 0; ks < 2; ++ks)
            a[ks] = *reinterpret_cast<const s16x8*>(&A[arow][ks * 32 + lq * 8]);
#pragma unroll
        for (int nt = 0; nt < 8; ++nt) {
            f32x4 accQ = {0.f, 0.f, 0.f, 0.f};
            f32x4 accP = {0.f, 0.f, 0.f, 0.f};
#pragma unroll
            for (int ks = 0; ks < 2; ++ks) {
                s16x8 bq = *reinterpret_cast<const s16x8*>(&Qw[(((nt << 1) + ks) * 64 + lane) * 8]);
                s16x8 bp = *reinterpret_cast<const s16x8*>(&Pw[(((nt << 1) + ks) * 64 + lane) * 8]);
                accQ = __builtin_amdgcn_mfma_f32_16x16x32_bf16(a[ks], bq, accQ, 0, 0, 0);
                accP = __builtin_amdgcn_mfma_f32_16x16x32_bf16(a[ks], bp, accP, 0, 0, 0);
            }
            int col = nt * 16 + lr;
            float bias = b1[col];
#pragma unroll
            for (int j = 0; j < 4; ++j) {
                int row = g0 + wave * 16 + lq * 4 + j;
                Qp[(size_t)row * 128 + col] = f2b(accQ[j] + bias);
                Pp[(size_t)row * 128 + col] = f2b(accP[j]);
            }
        }
    }
}

// K2a: column-wise exclusive prefix over histm[512][2048] in place; totals out.
__launch_bounds__(256)
__global__ void scan_cols(unsigned* __restrict__ histm, unsigned* __restrict__ total) {
    const int col = blockIdx.x * 256 + threadIdx.x;
    unsigned run = 0;
    for (int b = 0; b < SORTBLK; ++b) {
        unsigned v = histm[(size_t)b * NBKT2 + col];
        histm[(size_t)b * NBKT2 + col] = run;
        run += v;
    }
    total[col] = run;
}

// K2b: exclusive scan of 2048 bucket totals -> bucketBase[0..2048].
__launch_bounds__(256)
__global__ void scan_tot(const unsigned* __restrict__ total, unsigned* __restrict__ base) {
    __shared__ unsigned part[256];
    const int t = threadIdx.x;
    unsigned v[8]; unsigned s = 0;
#pragma unroll
    for (int i = 0; i < 8; ++i) { v[i] = total[t * 8 + i]; s += v[i]; }
    part[t] = s;
    __syncthreads();
    for (int off = 1; off < 256; off <<= 1) {
        unsigned x = (t >= off) ? part[t - off] : 0u;
        __syncthreads();
        part[t] += x;
        __syncthreads();
    }
    unsigned run = t ? part[t - 1] : 0u;
#pragma unroll
    for (int i = 0; i < 8; ++i) { base[t * 8 + i] = run; run += v[i]; }
    if (t == 255) base[NBKT2] = run;
}

// K3: deterministic scatter — LDS cursors seeded with exact global positions,
// fire-and-forget stores (zero global atomics).
// payload = dst[0:12) | w13[12:25) | seg_lo4[25:29)
__launch_bounds__(256, 8)
__global__ void sort_scatter(const int* __restrict__ eb, const int* __restrict__ esrc,
                             const int* __restrict__ edst, const float* __restrict__ evals,
                             const unsigned* __restrict__ histm,
                             const unsigned* __restrict__ base,
                             unsigned* __restrict__ payslot) {
    __shared__ unsigned cur[NBKT2];
    const int blk = blockIdx.x, tid = threadIdx.x;
    for (int i = tid; i < NBKT2; i += 256)
        cur[i] = base[i] + histm[(size_t)blk * NBKT2 + i];
    __syncthreads();
    const int e0 = blk * EPB;
#pragma unroll
    for (int i = 0; i < EPB / 256; ++i) {
        int e = e0 + i * 256 + tid;
        int seg = eb[e] * NN + esrc[e];
        unsigned wq = (unsigned)fminf(evals[e] * 8192.0f + 0.5f, 8191.0f);
        unsigned pay = (unsigned)edst[e] | (wq << 12) | ((unsigned)(seg & 15) << 25);
        unsigned pos = atomicAdd(&cur[seg >> 4], 1u);
        payslot[pos] = pay;
    }
}

// Pass B: one bucket (16 segments = 16 consecutive nodes) per block.
// Dense payload [gBase[bkt], gBase[bkt+1]), chunked <=1024 into LDS;
// 16-bin sort, scalarized reduce, MFMA gathered, fused node MLP.
__launch_bounds__(256, 6)
__global__ void bucket16_fused(const unsigned short* __restrict__ Qp,
                               const unsigned short* __restrict__ Pp,
                               const unsigned* __restrict__ payslot,
                               const unsigned* __restrict__ gBase,
                               const unsigned short* __restrict__ Wm2p,
                               const float* __restrict__ b2m,
                               const float* __restrict__ X,
                               const unsigned short* __restrict__ Wu1p,
                               const float* __restrict__ bu1,
                               const unsigned short* __restrict__ Wu2p,
                               const float* __restrict__ bu2,
                               float* __restrict__ out) {
    __shared__ unsigned raw[CHUNK];
    __shared__ unsigned sorted[CHUNK];
    __shared__ unsigned short S[16][136];
    __shared__ unsigned short A1[16][136];
    __shared__ unsigned short Hs[16][136];
    __shared__ unsigned h4[4][16];
    __shared__ unsigned curb4[4][16];
    __shared__ unsigned offs[17];
    __shared__ float SW[16], SC[16];
    const int tid = threadIdx.x, wv = tid >> 6, lane = tid & 63;
    // XCD-affine swizzle: blocks round-robin XCDs; give XCD x the buckets of batch x.
    const int bkt = (blockIdx.x & 7) * 256 + (blockIdx.x >> 3);
    const int node0 = bkt * SPB2;
    const int rowbase = (bkt >> 8) << 12;         // batch * NN

    // stage node feats into A1[:, 0:64]
#pragma unroll
    for (int i = 0; i < 4; ++i) {
        int idx = i * 256 + tid;
        int row = idx >> 6, f = idx & 63;
        A1[row][f] = f2b(X[(size_t)(node0 + row) * DNF + f]);
    }

    const unsigned* P32 = reinterpret_cast<const unsigned*>(Pp);
    const unsigned* Q32 = reinterpret_cast<const unsigned*>(Qp);
    const unsigned* PbS = P32 + (size_t)rowbase * 64;

    f32x2 q2[4], acc2[4];
    float wsum[4];
    unsigned scnt[4];
#pragma unroll
    for (int si = 0; si < 4; ++si) {
        int lo = wv * 4 + si;
        unsigned qv = Q32[(size_t)(node0 + lo) * 64 + lane];
        q2[si].x = uif(qv << 16); q2[si].y = uif(qv & 0xffff0000u);
        acc2[si].x = 0.f; acc2[si].y = 0.f;
        wsum[si] = 0.f; scnt[si] = 0u;
    }

    const unsigned start = gBase[bkt], end = gBase[bkt + 1];
    for (unsigned cbase = start; cbase < end; cbase += CHUNK) {
        const unsigned n = min((unsigned)CHUNK, end - cbase);
        if (tid < 64) ((unsigned*)h4)[tid] = 0;
        __syncthreads();
        for (unsigned i = tid; i < n; i += 256) {
            unsigned v = payslot[cbase + i];
            raw[i] = v;
            atomicAdd(&h4[wv][(v >> 25) & 15u], 1u);
        }
        __syncthreads();
        if (tid < 16) {                            // 16-bin scan of summed hist
            int xx = (int)(h4[0][tid] + h4[1][tid] + h4[2][tid] + h4[3][tid]);
#pragma unroll
            for (int o = 1; o < 16; o <<= 1) {
                int y = __shfl_up(xx, o);
                if (tid >= o) xx += y;
            }
            offs[tid + 1] = (unsigned)xx;
            if (tid == 0) offs[0] = 0;
        }
        __syncthreads();
        if (tid < 64) {                            // per-(wave,bin) disjoint cursors
            int w = tid >> 4, b = tid & 15;
            unsigned bse = offs[b];
            for (int w2 = 0; w2 < w; ++w2) bse += h4[w2][b];
            curb4[w][b] = bse;
        }
        __syncthreads();
        for (unsigned i = tid; i < n; i += 256) {  // LDS->LDS reorder
            unsigned v = raw[i];
            unsigned pos = atomicAdd(&curb4[wv][(v >> 25) & 15u], 1u);
            sorted[pos] = v;
        }
        __syncthreads();

#pragma unroll
        for (int si = 0; si < 4; ++si) {
            const int lo = wv * 4 + si;
            const unsigned s0 = offs[lo], s1 = offs[lo + 1];
            scnt[si] += s1 - s0;
            float wl = 0.f;
            for (unsigned i = s0 + lane; i < s1; i += 64)
                wl += (float)((sorted[i] >> 12) & 8191u);
            for (int m2 = 1; m2 < 64; m2 <<= 1) wl += __shfl_xor(wl, m2);
            wsum[si] += wl;

            for (unsigned bse = s0; bse < s1; bse += 8) {
                unsigned pv[8]; float wf[8];
#pragma unroll
                for (int k = 0; k < 8; ++k) {
                    unsigned idx = bse + (unsigned)k;
                    unsigned cu = (idx < s1) ? sorted[idx] : 0u;   // wave-uniform
                    int ci = __builtin_amdgcn_readfirstlane((int)cu);
                    wf[k] = (float)(unsigned)((ci >> 12) & 8191);  // integer-valued
                    int row = ci & 0xfff;
                    pv[k] = PbS[(size_t)row * 64 + lane];
                }
#pragma unroll
                for (int k = 0; k < 8; ++k) {
                    f32x2 p2 = { uif(pv[k] << 16), uif(pv[k] & 0xffff0000u) };
                    f32x2 h2 = q2[si] + p2;
                    h2 = __builtin_elementwise_max(h2, (f32x2){0.f, 0.f});
                    acc2[si] += wf[k] * h2;
                }
            }
        }
        __syncthreads();
    }

#pragma unroll
    for (int si = 0; si < 4; ++si) {
        const int lo = wv * 4 + si;
        unsigned sp = (unsigned)f2b(acc2[si].x) | ((unsigned)f2b(acc2[si].y) << 16);
        *reinterpret_cast<unsigned*>(&S[lo][2 * lane]) = sp;
        if (lane == 0) {
            SW[lo] = wsum[si];
            SC[lo] = (1.0f / 8192.0f) / (float)max(scnt[si], 1u);
        }
    }
    __syncthreads();

    const int lr = lane & 15, lq = lane >> 4;
    // gathered = (S @ Wm2 + sumw*b2) * SC -> A1[:, 64:128] (bf16)
    {
        s16x8 a[4];
#pragma unroll
        for (int ks = 0; ks < 4; ++ks)
            a[ks] = *reinterpret_cast<const s16x8*>(&S[lr][ks * 32 + lq * 8]);
        f32x4 acc = {0.f, 0.f, 0.f, 0.f};
#pragma unroll
        for (int ks = 0; ks < 4; ++ks) {
            s16x8 bf = *reinterpret_cast<const s16x8*>(&Wm2p[(((wv << 2) + ks) * 64 + lane) * 8]);
            acc = __builtin_amdgcn_mfma_f32_16x16x32_bf16(a[ks], bf, acc, 0, 0, 0);
        }
        float bb = b2m[wv * 16 + lr];
#pragma unroll
        for (int j = 0; j < 4; ++j) {
            int r = lq * 4 + j;
            float g = (acc[j] + SW[r] * bb) * SC[r];
            A1[r][64 + wv * 16 + lr] = f2b(g);
        }
    }
    __syncthreads();

    // node MLP layer 1: relu([X|gathered] @ Wu1 + bu1) -> Hs
    {
        s16x8 a1[4];
#pragma unroll
        for (int ks = 0; ks < 4; ++ks)
            a1[ks] = *reinterpret_cast<const s16x8*>(&A1[lr][ks * 32 + lq * 8]);
#pragma unroll
        for (int t = 0; t < 2; ++t) {
            int nt = wv * 2 + t;
            f32x4 acc = {0.f, 0.f, 0.f, 0.f};
#pragma unroll
            for (int ks = 0; ks < 4; ++ks) {
                s16x8 bf = *reinterpret_cast<const s16x8*>(&Wu1p[(((nt << 2) + ks) * 64 + lane) * 8]);
                acc = __builtin_amdgcn_mfma_f32_16x16x32_bf16(a1[ks], bf, acc, 0, 0, 0);
            }
            float bias = bu1[nt * 16 + lr];
#pragma unroll
            for (int j = 0; j < 4; ++j) {
                float hh = fmaxf(acc[j] + bias, 0.f);
                Hs[lq * 4 + j][nt * 16 + lr] = f2b(hh);
            }
        }
    }
    __syncthreads();

    // layer 2: Hs @ Wu2 + bu2 -> out
    {
        s16x8 a2[4];
#pragma unroll
        for (int ks = 0; ks < 4; ++ks)
            a2[ks] = *reinterpret_cast<const s16x8*>(&Hs[lr][ks * 32 + lq * 8]);
        f32x4 acc = {0.f, 0.f, 0.f, 0.f};
#pragma unroll
        for (int ks = 0; ks < 4; ++ks) {
            s16x8 bf = *reinterpret_cast<const s16x8*>(&Wu2p[(((wv << 2) + ks) * 64 + lane) * 8]);
            acc = __builtin_amdgcn_mfma_f32_16x16x32_bf16(a2[ks], bf, acc, 0, 0, 0);
        }
        float bias = bu2[wv * 16 + lr];
#pragma unroll
        for (int j = 0; j < 4; ++j)
            out[(size_t)(node0 + lq * 4 + j) * FF + wv * 16 + lr] = acc[j] + bias;
    }
}

// ---------------- legacy fallback (small ws) ----------------

template<int SCALE>
__launch_bounds__(256, 4)
__global__ void node_kernel(const float* __restrict__ node_feats,
                            const float* __restrict__ sums, const float* __restrict__ counts,
                            const unsigned short* __restrict__ W1p, const float* __restrict__ b1,
                            const unsigned short* __restrict__ W2p, const float* __restrict__ b2,
                            float* __restrict__ out) {
    __shared__ unsigned short A1[64][136];
    __shared__ unsigned short Hs[64][136];
    const int tid = threadIdx.x;
    const int g0 = blockIdx.x * 64;
    for (int i = 0; i < 16; ++i) {
        int idx = i * 256 + tid;
        int node = idx >> 6;
        int p = idx & 63;
        int g = g0 + node;
        float2 v;
        if (p < 32) {
            v = *reinterpret_cast<const float2*>(node_feats + (size_t)g * DNF + 2 * p);
        } else {
            float2 s = *reinterpret_cast<const float2*>(sums + (size_t)g * DM + 2 * p - 64);
            if (SCALE) {
                float scale = 1.0f / fmaxf(counts[g], 1.0f);
                s.x *= scale; s.y *= scale;
            }
            v = s;
        }
        unsigned packed = (unsigned)f2b(v.x) | ((unsigned)f2b(v.y) << 16);
        *reinterpret_cast<unsigned*>(&A1[node][2 * p]) = packed;
    }
    __syncthreads();
    const int wave = tid >> 6, lane = tid & 63;
    const int lr = lane & 15, lq = lane >> 4;
    const int arow = wave * 16 + lr;
    s16x8 a[4];
#pragma unroll
    for (int ks = 0; ks < 4; ++ks)
        a[ks] = *reinterpret_cast<const s16x8*>(&A1[arow][ks * 32 + lq * 8]);
#pragma unroll
    for (int nt = 0; nt < 8; ++nt) {
        f32x4 acc = {0.f, 0.f, 0.f, 0.f};
#pragma unroll
        for (int ks = 0; ks < 4; ++ks) {
            s16x8 bf = *reinterpret_cast<const s16x8*>(&W1p[(((nt << 2) + ks) * 64 + lane) * 8]);
            acc = __builtin_amdgcn_mfma_f32_16x16x32_bf16(a[ks], bf, acc, 0, 0, 0);
        }
        float bias = b1[nt * 16 + lr];
#pragma unroll
        for (int j = 0; j < 4; ++j) {
            float h = acc[j] + bias;
            h = h > 0.f ? h : 0.f;
            Hs[wave * 16 + lq * 4 + j][nt * 16 + lr] = f2b(h);
        }
    }
    s16x8 a2[4];
#pragma unroll
    for (int ks = 0; ks < 4; ++ks)
        a2[ks] = *reinterpret_cast<const s16x8*>(&Hs[arow][ks * 32 + lq * 8]);
#pragma unroll
    for (int nt = 0; nt < 4; ++nt) {
        f32x4 acc = {0.f, 0.f, 0.f, 0.f};
#pragma unroll
        for (int ks = 0; ks < 4; ++ks) {
            s16x8 bf = *reinterpret_cast<const s16x8*>(&W2p[(((nt << 2) + ks) * 64 + lane) * 8]);
            acc = __builtin_amdgcn_mfma_f32_16x16x32_bf16(a2[ks], bf, acc, 0, 0, 0);
        }
        float bias = b2[nt * 16 + lr];
#pragma unroll
        for (int j = 0; j < 4; ++j) {
            int g = g0 + wave * 16 + lq * 4 + j;
            out[(size_t)g * FF + nt * 16 + lr] = acc[j] + bias;
        }
    }
}

__launch_bounds__(256, 4)
__global__ void edge_kernel(const float* __restrict__ node_feats,
                            const int* __restrict__ eb, const int* __restrict__ esrc,
                            const int* __restrict__ edst, const float* __restrict__ evals,
                            const unsigned short* __restrict__ W1p, const float* __restrict__ b1,
                            const unsigned short* __restrict__ W2p, const float* __restrict__ b2,
                            float* __restrict__ sums, float* __restrict__ counts) {
    __shared__ unsigned short A1[64][136];
    __shared__ unsigned short Hs[64][136];
    const int tid = threadIdx.x;
    const int e0 = blockIdx.x * 64;
    if (tid < 64) {
        int e = e0 + tid;
        atomicAdd(&counts[eb[e] * NN + esrc[e]], 1.0f);
    }
    for (int i = 0; i < 16; ++i) {
        int idx = i * 256 + tid;
        int edge = idx >> 6;
        int p = idx & 63;
        int e = e0 + edge;
        int b = eb[e];
        const float* row;
        if (p < 32) row = node_feats + ((size_t)b * NN + esrc[e]) * DNF;
        else        row = node_feats + ((size_t)b * NN + edst[e]) * DNF - 64;
        float2 v = *reinterpret_cast<const float2*>(row + 2 * p);
        unsigned packed = (unsigned)f2b(v.x) | ((unsigned)f2b(v.y) << 16);
        *reinterpret_cast<unsigned*>(&A1[edge][2 * p]) = packed;
    }
    __syncthreads();
    const int wave = tid >> 6, lane = tid & 63;
    const int lr = lane & 15, lq = lane >> 4;
    const int arow = wave * 16 + lr;
    s16x8 a[4];
#pragma unroll
    for (int ks = 0; ks < 4; ++ks)
        a[ks] = *reinterpret_cast<const s16x8*>(&A1[arow][ks * 32 + lq * 8]);
#pragma unroll
    for (int nt = 0; nt < 8; ++nt) {
        f32x4 acc = {0.f, 0.f, 0.f, 0.f};
#pragma unroll
        for (int ks = 0; ks < 4; ++ks) {
            s16x8 bf = *reinterpret_cast<const s16x8*>(&W1p[(((nt << 2) + ks) * 64 + lane) * 8]);
            acc = __builtin_amdgcn_mfma_f32_16x16x32_bf16(a[ks], bf, acc, 0, 0, 0);
        }
        float bias = b1[nt * 16 + lr];
#pragma unroll
        for (int j = 0; j < 4; ++j) {
            float h = acc[j] + bias;
            h = h > 0.f ? h : 0.f;
            Hs[wave * 16 + lq * 4 + j][nt * 16 + lr] = f2b(h);
        }
    }
    s16x8 a2[4];
#pragma unroll
    for (int ks = 0; ks < 4; ++ks)
        a2[ks] = *reinterpret_cast<const s16x8*>(&Hs[arow][ks * 32 + lq * 8]);
    float ev[4]; int seg4[4];
#pragma unroll
    for (int j = 0; j < 4; ++j) {
        int r = e0 + wave * 16 + lq * 4 + j;
        ev[j] = evals[r];
        seg4[j] = eb[r] * NN + esrc[r];
    }
#pragma unroll
    for (int nt = 0; nt < 4; ++nt) {
        f32x4 acc = {0.f, 0.f, 0.f, 0.f};
#pragma unroll
        for (int ks = 0; ks < 4; ++ks) {
            s16x8 bf = *reinterpret_cast<const s16x8*>(&W2p[(((nt << 2) + ks) * 64 + lane) * 8]);
            acc = __builtin_amdgcn_mfma_f32_16x16x32_bf16(a2[ks], bf, acc, 0, 0, 0);
        }
        float bias = b2[nt * 16 + lr];
#pragma unroll
        for (int j = 0; j < 4; ++j) {
            float m = (acc[j] + bias) * ev[j];
            atomicAdd(&sums[(size_t)seg4[j] * DM + nt * 16 + lr], m);
        }
    }
}

extern "C" void kernel_launch(void* const* d_in, const int* in_sizes, int n_in,
                              void* d_out, int out_size, void* d_ws, size_t ws_size,
                              hipStream_t stream) {
    const float* node_feats = (const float*)d_in[0];
    const int*   eb    = (const int*)d_in[1];
    const int*   esrc  = (const int*)d_in[2];
    const int*   edst  = (const int*)d_in[3];
    const float* evals = (const float*)d_in[4];
    const float* Wm1 = (const float*)d_in[5];
    const float* bm1 = (const float*)d_in[6];
    const float* Wm2 = (const float*)d_in[7];
    const float* bm2 = (const float*)d_in[8];
    const float* Wu1 = (const float*)d_in[9];
    const float* bu1 = (const float*)d_in[10];
    const float* Wu2 = (const float*)d_in[11];
    const float* bu2 = (const float*)d_in[12];
    float* out = (float*)d_out;
    char* ws = (char*)d_ws;

    const size_t NEED = 25296896;
    if (ws_size >= NEED) {
        unsigned short* Qp      = (unsigned short*)(ws);              // 8 MB
        unsigned short* Pp      = (unsigned short*)(ws + 8388608);    // 8 MB
        unsigned*       payslot = (unsigned*)(ws + 16777216);         // 4 MB (dense)
        unsigned*       histm   = (unsigned*)(ws + 20971520);         // 512*2048*4 = 4 MB
        unsigned*       total   = (unsigned*)(ws + 25165824);         // 16 KB
        unsigned*       bbase   = (unsigned*)(ws + 25182208);         // 16 KB (2049 used)
        unsigned short* Qw      = (unsigned short*)(ws + 25198592);   // 16 KB
        unsigned short* Pw      = (unsigned short*)(ws + 25214976);   // 16 KB
        unsigned short* Wu1p    = (unsigned short*)(ws + 25231360);   // 32 KB
        unsigned short* Wu2p    = (unsigned short*)(ws + 25264128);   // 16 KB
        unsigned short* Wm2p    = (unsigned short*)(ws + 25280512);   // 16 KB

        pack_all<<<192, 256, 0, stream>>>(Wm1, Wm2, Wu1, Wu2, Qw, Pw, Wm2p, Wu1p, Wu2p);
        hist_pq<<<SORTBLK + 512, 256, 0, stream>>>(eb, esrc, histm,
                                                   node_feats, Qw, Pw, bm1, Qp, Pp);
        scan_cols<<<NBKT2 / 256, 256, 0, stream>>>(histm, total);
        scan_tot<<<1, 256, 0, stream>>>(total, bbase);
        sort_scatter<<<SORTBLK, 256, 0, stream>>>(eb, esrc, edst, evals,
                                                  histm, bbase, payslot);
        bucket16_fused<<<NBKT2, 256, 0, stream>>>(Qp, Pp, payslot, bbase,
                                                  Wm2p, bm2, node_feats,
                                                  Wu1p, bu1, Wu2p, bu2, out);
    } else {
        float* counts          = (float*)ws;
        unsigned short* W1p    = (unsigned short*)(ws + 131072);
        unsigned short* W2p    = (unsigned short*)(ws + 163840);
        unsigned short* Wu1p   = (unsigned short*)(ws + 180224);
        unsigned short* Wu2p   = (unsigned short*)(ws + 212992);
        hipMemsetAsync(d_out, 0, (size_t)out_size * sizeof(float), stream);
        hipMemsetAsync(counts, 0, 32768 * sizeof(float), stream);
        pack_weights<<<64, 256, 0, stream>>>(Wm1, W1p, 128, 128);
        pack_weights<<<32, 256, 0, stream>>>(Wm2, W2p, 128, 64);
        pack_weights<<<64, 256, 0, stream>>>(Wu1, Wu1p, 128, 128);
        pack_weights<<<32, 256, 0, stream>>>(Wu2, Wu2p, 128, 64);
        edge_kernel<<<NEDGE / 64, 256, 0, stream>>>(node_feats, eb, esrc, edst, evals,
                                                    W1p, bm1, W2p, bm2, out, counts);
        node_kernel<1><<<(NB * NN) / 64, 256, 0, stream>>>(node_feats, out, counts,
                                                           Wu1p, bu1, Wu2p, bu2, out);
    }
}